// Round 6
// baseline (862.134 us; speedup 1.0000x reference)
//
#include <hip/hip_runtime.h>
#include <math.h>

constexpr int Bn = 8, NZ = 16, Ln = 512;
constexpr int E = 256, DM = 512, NH = 16, HD = 32;
constexpr int FF = 1024, NL = 8, E1D = 32, PDIM = 64, PMAX = 24;
constexpr int ROWS = Bn * Ln;                       // 4096
constexpr float QSCALE = 0.04419417382415922f;      // 1/sqrt(512)

typedef __attribute__((ext_vector_type(8))) short bf16x8;
typedef __attribute__((ext_vector_type(4))) float floatx4;

__device__ inline unsigned short f2b(float f) {
  union { float f; unsigned u; } v; v.f = f;
  unsigned r = (v.u + 0x7FFF + ((v.u >> 16) & 1)) >> 16;
  return (unsigned short)r;
}
__device__ inline float b2f(unsigned short u) {
  union { unsigned u; float f; } v; v.u = ((unsigned)u) << 16; return v.f;
}

// async global->LDS DMA, 16B per lane; LDS dest is wave-uniform base + lane*16
// (m104 semantics). Compiler drains vmcnt(0) at __syncthreads -> data visible.
__device__ inline void gll16(const void* g, void* l) {
  __builtin_amdgcn_global_load_lds(
      (const __attribute__((address_space(1))) void*)g,
      (__attribute__((address_space(3))) void*)l, 16, 0, 0);
}

// ---------------------------------------------------------------------------
// batched Wq/Wk/Wv fp32 [l][E][DM] -> bf16 qkvT [l][3*DM][E]
// ---------------------------------------------------------------------------
__global__ __launch_bounds__(256) void transpose_qkv(
    const float* __restrict__ Wq, const float* __restrict__ Wk,
    const float* __restrict__ Wv, unsigned short* __restrict__ qkvT)
{
  __shared__ float t[32][33];
  int zb = blockIdx.z;
  int which = zb / NL, l = zb % NL;
  const float* s = (which == 0 ? Wq : which == 1 ? Wk : Wv) + (size_t)l * E * DM;
  unsigned short* d = qkvT + (size_t)l * 3 * DM * E + (size_t)which * DM * E;
  int c0 = blockIdx.x * 32, r0 = blockIdx.y * 32;
  int tx = threadIdx.x & 31, ty = threadIdx.x >> 5;
  #pragma unroll
  for (int i = 0; i < 4; ++i)
    t[ty + i * 8][tx] = s[(size_t)(r0 + ty + i * 8) * DM + c0 + tx];
  __syncthreads();
  #pragma unroll
  for (int i = 0; i < 4; ++i)
    d[(size_t)(c0 + ty + i * 8) * E + r0 + tx] = f2b(t[tx][ty + i * 8]);
}

// ---------------------------------------------------------------------------
// generic fp32 [l][R][C] -> bf16 [l][C][R]
// ---------------------------------------------------------------------------
__global__ __launch_bounds__(256) void transpose_bf16(
    const float* __restrict__ src, unsigned short* __restrict__ dst,
    int R, int C, size_t sls, size_t dls)
{
  __shared__ float t[32][33];
  int l = blockIdx.z;
  int c0 = blockIdx.x * 32, r0 = blockIdx.y * 32;
  int tx = threadIdx.x & 31, ty = threadIdx.x >> 5;
  const float* s = src + (size_t)l * sls;
  unsigned short* d = dst + (size_t)l * dls;
  #pragma unroll
  for (int i = 0; i < 4; ++i)
    t[ty + i * 8][tx] = s[(size_t)(r0 + ty + i * 8) * C + c0 + tx];
  __syncthreads();
  #pragma unroll
  for (int i = 0; i < 4; ++i)
    d[(size_t)(c0 + ty + i * 8) * R + r0 + tx] = f2b(t[tx][ty + i * 8]);
}

// ---------------------------------------------------------------------------
// embed stage 1: t0 = relu(z^T @ ex_w1 + b1) fp32; e_aa gather into umb
// ---------------------------------------------------------------------------
__global__ __launch_bounds__(256) void embed1_kernel(
    const float* __restrict__ z, const float* __restrict__ x,
    const float* __restrict__ aa,
    const float* __restrict__ w1, const float* __restrict__ b1,
    float* __restrict__ t0, unsigned short* __restrict__ umb)
{
  int row = blockIdx.x;
  int b = row >> 9, l = row & (Ln - 1);
  int t = threadIdx.x;
  __shared__ float zs[NZ];
  __shared__ int am_s;
  if (t < NZ) zs[t] = z[((size_t)b * NZ + t) * Ln + l];
  if (t == 0) {
    const float* xp = x + (size_t)b * 20 * Ln + l;
    int am = 0; float bv = xp[0];
    for (int c = 1; c < 20; ++c) { float vv = xp[(size_t)c * Ln]; if (vv > bv) { bv = vv; am = c; } }
    am_s = am;
  }
  __syncthreads();
  float a1 = b1[t];
  #pragma unroll
  for (int nz = 0; nz < NZ; ++nz) a1 += zs[nz] * w1[nz * E + t];
  t0[(size_t)row * E + t] = fmaxf(a1, 0.f);
  if (t < E1D) umb[(size_t)row * (E + E1D) + E + t] = f2b(aa[am_s * E1D + t]);
}

// ---------------------------------------------------------------------------
// pairwise-bias collapse: 49 bins per (layer, head)
// ---------------------------------------------------------------------------
__global__ __launch_bounds__(256) void bias_kernel(
    const float* __restrict__ pos, const float* __restrict__ W2d,
    const float* __restrict__ b2d, float* __restrict__ bias49)
{
  int layer = blockIdx.x;
  for (int idx = threadIdx.x; idx < NH * 49; idx += 256) {
    int hh = idx / 49, bin = idx % 49;
    float acc = b2d[layer * NH + hh];
    for (int p = 0; p < PDIM; ++p)
      acc += pos[bin * PDIM + p] * W2d[((size_t)layer * PDIM + p) * NH + hh];
    bias49[(size_t)layer * NH * 49 + hh * 49 + bin] = acc;
  }
}

// ---------------------------------------------------------------------------
// bf16 MFMA GEMM. BK in {32, 128}. (R17-proven, unchanged)
// ---------------------------------------------------------------------------
template<int BM, int BN, int BK, bool BIAS, bool RELU, bool OUTBF16, bool QKV>
__global__ __launch_bounds__(256) void gemm_mfma(
    const unsigned short* __restrict__ A, const unsigned short* __restrict__ Bt,
    const float* __restrict__ bias,
    float* __restrict__ Cf, unsigned short* __restrict__ Cb, int N, int K)
{
  constexpr int MT = BM / 32, NT = BN / 32;
  __shared__ __align__(16) unsigned short As[BM][BK];
  __shared__ __align__(16) unsigned short Bs[BN][BK];
  const int tid = threadIdx.x;
  const int wave = tid >> 6, ln = tid & 63;
  const int quad = ln >> 4, l16 = ln & 15;
  const int wm = wave >> 1, wn = wave & 1;
  const int m0 = blockIdx.y * BM, n0 = blockIdx.x * BN;

  floatx4 acc[MT][NT] = {};

  if constexpr (BK == 32) {
    // 16 rows per wave-issue, 4x16B chunks per 64B row
    const int lrow = ln >> 2, chunk = ln & 3;
    const int schunk = chunk ^ ((lrow >> 1) & 3);
    const unsigned short* aSrc = A + (size_t)(m0 + wave * 16 + lrow) * K + schunk * 8;
    const unsigned short* bSrc = Bt + (size_t)(n0 + wave * 16 + lrow) * K + schunk * 8;
    const int rkey = (l16 >> 1) & 3;

    for (int kb = 0; kb < K; kb += 32) {
      __syncthreads();
      #pragma unroll
      for (int it = 0; it < BM / 64; ++it)
        gll16(aSrc + (size_t)it * 64 * K + kb, &As[it * 64 + wave * 16][0]);
      #pragma unroll
      for (int it = 0; it < BN / 64; ++it)
        gll16(bSrc + (size_t)it * 64 * K + kb, &Bs[it * 64 + wave * 16][0]);
      __syncthreads();
      bf16x8 af[MT], bfr[NT];
      #pragma unroll
      for (int i = 0; i < MT; ++i)
        af[i] = *(const bf16x8*)&As[wm * (BM / 2) + i * 16 + l16][(quad ^ rkey) * 8];
      #pragma unroll
      for (int j = 0; j < NT; ++j)
        bfr[j] = *(const bf16x8*)&Bs[wn * (BN / 2) + j * 16 + l16][(quad ^ rkey) * 8];
      #pragma unroll
      for (int i = 0; i < MT; ++i)
        #pragma unroll
        for (int j = 0; j < NT; ++j)
          acc[i][j] = __builtin_amdgcn_mfma_f32_16x16x32_bf16(af[i], bfr[j], acc[i][j], 0, 0, 0);
    }
  } else {
    // BK=128: 4 rows per wave-issue, 16x16B chunks per 256B row.
    const int lrow = ln >> 4, chunk = ln & 15;
    const int key = wave * 4 + lrow;              // < 16
    const int schunk = chunk ^ key;
    const unsigned short* aSrc = A + (size_t)(m0 + key) * K + schunk * 8;
    const unsigned short* bSrc = Bt + (size_t)(n0 + key) * K + schunk * 8;

    for (int kb = 0; kb < K; kb += 128) {
      __syncthreads();
      #pragma unroll
      for (int it = 0; it < BM / 16; ++it)
        gll16(aSrc + (size_t)(it * 16) * K + kb, &As[it * 16 + wave * 4][0]);
      #pragma unroll
      for (int it = 0; it < BN / 16; ++it)
        gll16(bSrc + (size_t)(it * 16) * K + kb, &Bs[it * 16 + wave * 4][0]);
      __syncthreads();
      #pragma unroll
      for (int kc = 0; kc < 4; ++kc) {
        bf16x8 af[MT], bfr[NT];
        #pragma unroll
        for (int i = 0; i < MT; ++i)
          af[i] = *(const bf16x8*)&As[wm * (BM / 2) + i * 16 + l16][(((kc * 4 + quad) ^ l16) * 8)];
        #pragma unroll
        for (int j = 0; j < NT; ++j)
          bfr[j] = *(const bf16x8*)&Bs[wn * (BN / 2) + j * 16 + l16][(((kc * 4 + quad) ^ l16) * 8)];
        #pragma unroll
        for (int i = 0; i < MT; ++i)
          #pragma unroll
          for (int j = 0; j < NT; ++j)
            acc[i][j] = __builtin_amdgcn_mfma_f32_16x16x32_bf16(af[i], bfr[j], acc[i][j], 0, 0, 0);
      }
    }
  }

  #pragma unroll
  for (int i = 0; i < MT; ++i)
    #pragma unroll
    for (int j = 0; j < NT; ++j) {
      int col = n0 + wn * (BN / 2) + j * 16 + l16;
      float bv = BIAS ? bias[col] : 0.f;
      float sc = QKV ? (col < 512 ? QSCALE : 1.f) : 1.f;
      #pragma unroll
      for (int r = 0; r < 4; ++r) {
        int rowg = m0 + wm * (BM / 2) + i * 16 + quad * 4 + r;
        float v = acc[i][j][r] * sc + bv;
        if (RELU) v = fmaxf(v, 0.f);
        if (OUTBF16) Cb[(size_t)rowg * N + col] = f2b(v);
        else Cf[(size_t)rowg * N + col] = v;
      }
    }
}

// ---------------------------------------------------------------------------
// Fused GEMM(+bias+resid) + LayerNorm, N = 256. (R17-proven, unchanged)
// ---------------------------------------------------------------------------
__global__ __launch_bounds__(256) void gemm_ln(
    const unsigned short* __restrict__ A, const unsigned short* __restrict__ Bt,
    const float* __restrict__ bias, float* __restrict__ h,
    const float* __restrict__ g, const float* __restrict__ be,
    unsigned short* __restrict__ outb, int bstride, int K)
{
  __shared__ __align__(16) unsigned short As[16][128];
  __shared__ __align__(16) unsigned short Bs[256][128];
  __shared__ __align__(16) float vtile[16][260];   // +4 pad: scatter 2-way max
  const int tid = threadIdx.x;
  const int w = tid >> 6, ln = tid & 63;
  const int quad = ln >> 4, l16 = ln & 15;
  const int m0 = blockIdx.x * 16;
  const int lrow = ln >> 4, chunk = ln & 15;
  const int key = w * 4 + lrow;                   // row & 15
  const int schunk = chunk ^ key;
  const unsigned short* aSrc = A + (size_t)(m0 + key) * K + schunk * 8;
  const unsigned short* bSrc = Bt + (size_t)key * K + schunk * 8;

  floatx4 acc[4] = {};

  for (int kb = 0; kb < K; kb += 128) {
    __syncthreads();
    gll16(aSrc + kb, &As[w * 4][0]);
    #pragma unroll
    for (int it = 0; it < 16; ++it)
      gll16(bSrc + (size_t)(it * 16) * K + kb, &Bs[it * 16 + w * 4][0]);
    __syncthreads();
    #pragma unroll
    for (int kc = 0; kc < 4; ++kc) {
      bf16x8 af = *(const bf16x8*)&As[l16][(((kc * 4 + quad) ^ l16) * 8)];
      #pragma unroll
      for (int nt = 0; nt < 4; ++nt) {
        bf16x8 bf = *(const bf16x8*)&Bs[w * 64 + nt * 16 + l16][(((kc * 4 + quad) ^ l16) * 8)];
        acc[nt] = __builtin_amdgcn_mfma_f32_16x16x32_bf16(af, bf, acc[nt], 0, 0, 0);
      }
    }
  }

  // v = (acc + bias) + resid — same op order as old gemm_n256 epilogue
  #pragma unroll
  for (int nt = 0; nt < 4; ++nt) {
    int col = w * 64 + nt * 16 + l16;
    float bv = bias[col];
    #pragma unroll
    for (int r = 0; r < 4; ++r) {
      int row = quad * 4 + r;
      vtile[row][col] = acc[nt][r] + bv + h[(size_t)(m0 + row) * E + col];
    }
  }
  __syncthreads();

  // LN phase — bitwise replica of ln_kernel (wave-per-row, float4 lanes)
  const int c0 = ln * 4;
  #pragma unroll
  for (int rr = 0; rr < 4; ++rr) {
    const int lr = w * 4 + rr;
    float4 v = *(const float4*)&vtile[lr][c0];
    float s = v.x + v.y + v.z + v.w;
    float s2 = v.x * v.x + v.y * v.y + v.z * v.z + v.w * v.w;
    #pragma unroll
    for (int off = 1; off < 64; off <<= 1) {
      s += __shfl_xor(s, off, 64);
      s2 += __shfl_xor(s2, off, 64);
    }
    const float mean = s * (1.f / E);
    const float rstd = rsqrtf(s2 * (1.f / E) - mean * mean + 1e-5f);
    const float4 gv = *(const float4*)(g + c0);
    const float4 bv = *(const float4*)(be + c0);
    float4 y;
    y.x = (v.x - mean) * rstd * gv.x + bv.x;
    y.y = (v.y - mean) * rstd * gv.y + bv.y;
    y.z = (v.z - mean) * rstd * gv.z + bv.z;
    y.w = (v.w - mean) * rstd * gv.w + bv.w;
    const size_t row = (size_t)(m0 + lr);
    *(float4*)(h + row * E + c0) = y;
    ushort4 yb;
    yb.x = f2b(y.x); yb.y = f2b(y.y); yb.z = f2b(y.z); yb.w = f2b(y.w);
    *(ushort4*)(outb + row * (size_t)bstride + c0) = yb;
  }
}

// ---------------------------------------------------------------------------
// MFMA flash attention. R18: QBLK 64->128 (grid 1024->512 blocks) with two
// sequential Q-fragments per wave (Pw per-wave buffer reused; per-wave DS
// ops are in-order so no barrier between u=0/u=1). Single barrier per
// j-tile via K/V double-buffer + async-stage split (T14): write(cur) ->
// barrier -> issue jt+1 loads -> compute(cur). Hazard: write(jt+1,buf^1)
// vs read(jt-1,buf^1) separated by barrier(jt); waves lag <=1 phase past
// a barrier. Per-q-row scalar/MFMA/shuffle sequence is IDENTICAL to R17
// (same lane placement within 16-lane groups) -> bitwise-identical output.
// ---------------------------------------------------------------------------
__global__ __launch_bounds__(256) void attn_kernel(
    const unsigned short* __restrict__ qkv, const float* __restrict__ bias49,
    unsigned short* __restrict__ o)
{
  const int i0 = blockIdx.x * 128;
  const int bh = blockIdx.y;
  const int b = bh >> 4, hh = bh & 15;
  const int tid = threadIdx.x;
  const int wave = tid >> 6, ln = tid & 63;
  const int quad = ln >> 4, l16 = ln & 15;

  __shared__ __align__(16) unsigned short Kt[2][64][40];
  __shared__ __align__(16) unsigned short Vt[2][32][72];
  __shared__ __align__(16) unsigned short Pw[4][2][16][72];
  __shared__ float bsh[49];

  if (tid < 49) bsh[tid] = bias49[hh * 49 + tid];

  const unsigned short* qkvb = qkv + (size_t)b * Ln * 1536;

  bf16x8 qf[2];
  #pragma unroll
  for (int u = 0; u < 2; ++u) {
    const int qrow = i0 + wave * 32 + u * 16 + l16;
    qf[u] = *(const bf16x8*)(qkvb + (size_t)qrow * 1536 + hh * 32 + quad * 8);
  }

  float m[2][4], l[2][4];
  #pragma unroll
  for (int u = 0; u < 2; ++u)
    #pragma unroll
    for (int r = 0; r < 4; ++r) { m[u][r] = -1e30f; l[u][r] = 0.f; }
  floatx4 acc_o[2][2] = {};

  const int krow = tid >> 2, kch = (tid & 3) * 8;
  const int vkey = tid & 63, vch = (tid >> 6) * 8;
  const unsigned short* kp = qkvb + (size_t)krow * 1536 + 512 + hh * 32 + kch;
  const unsigned short* vp = qkvb + (size_t)vkey * 1536 + 1024 + hh * 32 + vch;

  float4 kreg = *(const float4*)kp;
  bf16x8 vreg = *(const bf16x8*)vp;

  for (int jt = 0; jt < 8; ++jt) {
    const int j0 = jt * 64;
    const int cur = jt & 1;
    *(float4*)&Kt[cur][krow][kch] = kreg;
    #pragma unroll
    for (int i = 0; i < 8; ++i) Vt[cur][vch + i][vkey] = (unsigned short)vreg[i];
    __syncthreads();
    if (jt < 7) {   // issue next tile's loads; latency hides under compute
      kreg = *(const float4*)(kp + (size_t)(j0 + 64) * 1536);
      vreg = *(const bf16x8*)(vp + (size_t)(j0 + 64) * 1536);
    }

    #pragma unroll
    for (int u = 0; u < 2; ++u) {
      const int qbase = i0 + wave * 32 + u * 16;

      floatx4 s4[4];
      #pragma unroll
      for (int t = 0; t < 4; ++t) {
        bf16x8 kf = *(const bf16x8*)&Kt[cur][16 * t + l16][quad * 8];
        s4[t] = __builtin_amdgcn_mfma_f32_16x16x32_bf16(qf[u], kf, (floatx4){0.f, 0.f, 0.f, 0.f}, 0, 0, 0);
      }
      const int relmin = j0 - (qbase + 15), relmax = j0 + 63 - qbase;
      if (relmin >= PMAX) {
        float bc = bsh[48];
        #pragma unroll
        for (int t = 0; t < 4; ++t)
          #pragma unroll
          for (int r = 0; r < 4; ++r) s4[t][r] += bc;
      } else if (relmax <= -PMAX) {
        float bc = bsh[0];
        #pragma unroll
        for (int t = 0; t < 4; ++t)
          #pragma unroll
          for (int r = 0; r < 4; ++r) s4[t][r] += bc;
      } else {
        const int base_rel = (j0 + l16) - (qbase + quad * 4);
        #pragma unroll
        for (int t = 0; t < 4; ++t)
          #pragma unroll
          for (int r = 0; r < 4; ++r) {
            int rel = base_rel + 16 * t - r;
            rel = rel < -PMAX ? -PMAX : (rel > PMAX ? PMAX : rel);
            s4[t][r] += bsh[rel + PMAX];
          }
      }

      float mloc[4], alpha[4], psum[4];
      #pragma unroll
      for (int r = 0; r < 4; ++r) {
        mloc[r] = fmaxf(fmaxf(s4[0][r], s4[1][r]), fmaxf(s4[2][r], s4[3][r]));
        #pragma unroll
        for (int off = 1; off < 16; off <<= 1)
          mloc[r] = fmaxf(mloc[r], __shfl_xor(mloc[r], off, 64));
        float mnew = fmaxf(m[u][r], mloc[r]);
        alpha[r] = __expf(m[u][r] - mnew);
        m[u][r] = mnew;
        psum[r] = 0.f;
      }
      #pragma unroll
      for (int t = 0; t < 4; ++t)
        #pragma unroll
        for (int r = 0; r < 4; ++r) {
          float p = __expf(s4[t][r] - m[u][r]);
          s4[t][r] = p;
          psum[r] += p;
        }
      #pragma unroll
      for (int r = 0; r < 4; ++r) {
        #pragma unroll
        for (int off = 1; off < 16; off <<= 1)
          psum[r] += __shfl_xor(psum[r], off, 64);
        l[u][r] = l[u][r] * alpha[r] + psum[r];
        acc_o[u][0][r] *= alpha[r];
        acc_o[u][1][r] *= alpha[r];
      }

      #pragma unroll
      for (int t = 0; t < 4; ++t)
        #pragma unroll
        for (int r = 0; r < 4; ++r) {
          float p = s4[t][r];
          unsigned short hi = f2b(p);
          unsigned short lo = f2b(p - b2f(hi));
          Pw[wave][0][quad * 4 + r][16 * t + l16] = hi;
          Pw[wave][1][quad * 4 + r][16 * t + l16] = lo;
        }

      #pragma unroll
      for (int kh = 0; kh < 2; ++kh) {
        bf16x8 phi = *(const bf16x8*)&Pw[wave][0][l16][kh * 32 + quad * 8];
        bf16x8 plo = *(const bf16x8*)&Pw[wave][1][l16][kh * 32 + quad * 8];
        #pragma unroll
        for (int nt = 0; nt < 2; ++nt) {
          bf16x8 vf = *(const bf16x8*)&Vt[cur][nt * 16 + l16][kh * 32 + quad * 8];
          acc_o[u][nt] = __builtin_amdgcn_mfma_f32_16x16x32_bf16(phi, vf, acc_o[u][nt], 0, 0, 0);
          acc_o[u][nt] = __builtin_amdgcn_mfma_f32_16x16x32_bf16(plo, vf, acc_o[u][nt], 0, 0, 0);
        }
      }
    }
  }

  #pragma unroll
  for (int u = 0; u < 2; ++u)
    #pragma unroll
    for (int r = 0; r < 4; ++r) {
      float inv = 1.f / l[u][r];
      size_t rowg = (size_t)b * Ln + i0 + wave * 32 + u * 16 + quad * 4 + r;
      #pragma unroll
      for (int nt = 0; nt < 2; ++nt)
        o[rowg * 512 + hh * 32 + nt * 16 + l16] = f2b(acc_o[u][nt][r] * inv);
    }
}

// ---------------------------------------------------------------------------
// fp32 tiled GEMM: C = act(A@B + bias), optional bf16 mirror (embed2 / head)
// ---------------------------------------------------------------------------
template<bool RELU, bool BIAS, bool MIRROR>
__global__ __launch_bounds__(256) void gemm64f(
    const float* __restrict__ A, const float* __restrict__ B,
    const float* __restrict__ bias, float* __restrict__ C,
    unsigned short* __restrict__ mir, int N, int K)
{
  __shared__ __align__(16) float As[16][64];
  __shared__ __align__(16) float Bss[16][68];
  const int tid = threadIdx.x;
  const int tx = tid & 15, ty = tid >> 4;
  const int m0 = blockIdx.y * 64, n0 = blockIdx.x * 64;
  const int arow = tid >> 2, acol = (tid & 3) * 4;
  const int brow = tid >> 6, bcol = tid & 63;
  float acc[4][4] = {};
  for (int kb = 0; kb < K; kb += 16) {
    __syncthreads();
    float4 av = *(const float4*)(A + (size_t)(m0 + arow) * K + kb + acol);
    As[acol + 0][arow] = av.x; As[acol + 1][arow] = av.y;
    As[acol + 2][arow] = av.z; As[acol + 3][arow] = av.w;
    #pragma unroll
    for (int kk = 0; kk < 4; ++kk)
      Bss[brow + kk * 4][bcol] = B[(size_t)(kb + brow + kk * 4) * N + n0 + bcol];
    __syncthreads();
    #pragma unroll
    for (int k = 0; k < 16; ++k) {
      float4 a = *(const float4*)&As[k][4 * ty];
      float4 b = *(const float4*)&Bss[k][4 * tx];
      float av4[4] = {a.x, a.y, a.z, a.w};
      float bv4[4] = {b.x, b.y, b.z, b.w};
      #pragma unroll
      for (int ii = 0; ii < 4; ++ii)
        #pragma unroll
        for (int jj = 0; jj < 4; ++jj)
          acc[ii][jj] += av4[ii] * bv4[jj];
    }
  }
  #pragma unroll
  for (int ii = 0; ii < 4; ++ii) {
    size_t row = (size_t)m0 + 4 * ty + ii;
    int col = n0 + 4 * tx;
    float4 vv;
    vv.x = acc[ii][0]; vv.y = acc[ii][1]; vv.z = acc[ii][2]; vv.w = acc[ii][3];
    if (BIAS) {
      float4 bb = *(const float4*)(bias + col);
      vv.x += bb.x; vv.y += bb.y; vv.z += bb.z; vv.w += bb.w;
    }
    if (RELU) {
      vv.x = fmaxf(vv.x, 0.f); vv.y = fmaxf(vv.y, 0.f);
      vv.z = fmaxf(vv.z, 0.f); vv.w = fmaxf(vv.w, 0.f);
    }
    *(float4*)(C + row * N + col) = vv;
    if (MIRROR) {
      ushort4 mv;
      mv.x = f2b(vv.x); mv.y = f2b(vv.y); mv.z = f2b(vv.z); mv.w = f2b(vv.w);
      *(ushort4*)(mir + row * N + col) = mv;
    }
  }
}

__global__ __launch_bounds__(256) void final_r_kernel(
    const float* __restrict__ t1, const float* __restrict__ w2,
    const float* __restrict__ b2, float* __restrict__ r)
{
  int row = blockIdx.x, t = threadIdx.x;
  float xv = t1[(size_t)row * E + t];
  float p0 = xv * w2[t * 3 + 0];
  float p1 = xv * w2[t * 3 + 1];
  float p2 = xv * w2[t * 3 + 2];
  #pragma unroll
  for (int off = 32; off > 0; off >>= 1) {
    p0 += __shfl_down(p0, off, 64);
    p1 += __shfl_down(p1, off, 64);
    p2 += __shfl_down(p2, off, 64);
  }
  __shared__ float red[4][3];
  if ((t & 63) == 0) { int w = t >> 6; red[w][0] = p0; red[w][1] = p1; red[w][2] = p2; }
  __syncthreads();
  if (t < 3)
    r[(size_t)row * 3 + t] = red[0][t] + red[1][t] + red[2][t] + red[3][t] + b2[t];
}

__global__ __launch_bounds__(512) void dist_kernel(
    const float* __restrict__ r, float* __restrict__ out)
{
  int bi = blockIdx.x;
  int j = threadIdx.x;
  int b = bi >> 9;
  float x0 = r[(size_t)bi * 3 + 0];
  float y0 = r[(size_t)bi * 3 + 1];
  float z0 = r[(size_t)bi * 3 + 2];
  const float* rj = r + ((size_t)b * Ln + j) * 3;
  float dx = rj[0] - x0, dy = rj[1] - y0, dz = rj[2] - z0;
  out[(size_t)bi * Ln + j] = sqrtf(dx * dx + dy * dy + dz * dz + 1e-12f);
}

// ---------------------------------------------------------------------------
extern "C" void kernel_launch(void* const* d_in, const int* in_sizes, int n_in,
                              void* d_out, int out_size, void* d_ws, size_t ws_size,
                              hipStream_t stream)
{
  const float* z     = (const float*)d_in[0];
  const float* x     = (const float*)d_in[1];
  const float* pos   = (const float*)d_in[2];
  const float* aa    = (const float*)d_in[3];
  const float* ex_w1 = (const float*)d_in[4];
  const float* ex_b1 = (const float*)d_in[5];
  const float* ex_w2 = (const float*)d_in[6];
  const float* ex_b2 = (const float*)d_in[7];
  const float* Wq    = (const float*)d_in[8];
  const float* Wk    = (const float*)d_in[9];
  const float* Wv    = (const float*)d_in[10];
  const float* Wo    = (const float*)d_in[11];
  const float* bo    = (const float*)d_in[12];
  const float* W2d   = (const float*)d_in[13];
  const float* b2d   = (const float*)d_in[14];
  const float* W1    = (const float*)d_in[15];
  const float* b1    = (const float*)d_in[16];
  const float* W2    = (const float*)d_in[17];
  const float* b2    = (const float*)d_in[18];
  const float* g1    = (const float*)d_in[19];
  const float* be1   = (const float*)d_in[20];
  const float* g2    = (const float*)d_in[21];
  const float* be2   = (const float*)d_in[22];
  const float* m3w1  = (const float*)d_in[23];
  const float* m3b1  = (const float*)d_in[24];
  const float* m3w2  = (const float*)d_in[25];
  const float* m3b2  = (const float*)d_in[26];

  float* ws     = (float*)d_ws;
  float* h      = ws;                          // 4096*256
  float* t0     = h + (size_t)ROWS * E;        // 4096*256 (embed hidden / tmp)
  float* r      = t0 + (size_t)ROWS * E;       // 4096*3
  float* bias49 = r + (size_t)ROWS * 3;        // 8*16*49
  unsigned short* us = (unsigned short*)(bias49 + NL * NH * 49);
  unsigned short* hb   = us;                              // 4096*256
  unsigned short* umb  = hb  + (size_t)ROWS * E;          // 4096*288
  unsigned short* qkvb = umb + (size_t)ROWS * (E + E1D);  // 4096*1536
  unsigned short* ob   = qkvb + (size_t)ROWS * 3 * DM;    // 4096*512
  unsigned short* t1b  = ob  + (size_t)ROWS * DM;         // 4096*1024
  unsigned short* qkvT = t1b + (size_t)ROWS * FF;         // 8*1536*256
  unsigned short* WoT  = qkvT + (size_t)NL * 3 * DM * E;  // 8*256*512
  unsigned short* W1T  = WoT  + (size_t)NL * E * DM;      // 8*1024*288
  unsigned short* W2T  = W1T  + (size_t)NL * FF * (E+E1D);// 8*256*1024
  float* t1f = (float*)t1b;   // head scratch aliases t1b

  // ---- weight transpose+convert (4 launches) ----
  transpose_qkv<<<dim3(DM/32, E/32, 3*NL), 256, 0, stream>>>(Wq, Wk, Wv, qkvT);
  transpose_bf16<<<dim3(E/32, DM/32, NL), 256, 0, stream>>>(
      Wo, WoT, DM, E, (size_t)DM * E, (size_t)DM * E);
  transpose_bf16<<<dim3(FF/32, (E+E1D)/32, NL), 256, 0, stream>>>(
      W1, W1T, E + E1D, FF, (size_t)(E+E1D) * FF, (size_t)(E+E1D) * FF);
  transpose_bf16<<<dim3(E/32, FF/32, NL), 256, 0, stream>>>(
      W2, W2T, FF, E, (size_t)FF * E, (size_t)FF * E);

  embed1_kernel<<<ROWS, 256, 0, stream>>>(z, x, aa, ex_w1, ex_b1, t0, umb);
  gemm64f<false,true,true><<<dim3(E/64, ROWS/64), 256, 0, stream>>>(
      t0, ex_w2, ex_b2, h, hb, E, E);
  bias_kernel<<<NL, 256, 0, stream>>>(pos, W2d, b2d, bias49);

  for (int i = 0; i < NL; ++i) {
    // fused QKV: N=1536, 64x128 tiles, BK=128 -> 768 blocks (3/CU), 2 K-steps
    gemm_mfma<64,128,128,false,false,true,true><<<dim3(12, 64), 256, 0, stream>>>(
        hb, qkvT + (size_t)i * 3 * DM * E, nullptr, nullptr, qkvb, 3 * DM, E);
    // attention: QBLK=128 -> grid (4, 128) = 512 blocks
    attn_kernel<<<dim3(Ln/128, Bn*NH), 256, 0, stream>>>(
        qkvb, bias49 + (size_t)i * NH * 49, ob);
    // fused Wo + bias + resid + LN1 -> h, umb  (256 blocks, 4 K-steps)
    gemm_ln<<<ROWS/16, 256, 0, stream>>>(
        ob, WoT + (size_t)i * DM * E, bo + (size_t)i * E, h,
        g1 + (size_t)i * E, be1 + (size_t)i * E, umb, E + E1D, DM);
    // FF1 + bias + relu -> bf16 t1b  (64x64 tiles, BK=32 -> 1024 blocks, 4/CU)
    gemm_mfma<64,64,32,true,true,true,false><<<dim3(FF/64, ROWS/64), 256, 0, stream>>>(
        umb, W1T + (size_t)i * FF * (E+E1D), b1 + (size_t)i * FF, nullptr, t1b, FF, E + E1D);
    // fused FF2 + bias + resid + LN2 -> h, hb  (256 blocks, 8 K-steps)
    gemm_ln<<<ROWS/16, 256, 0, stream>>>(
        t1b, W2T + (size_t)i * E * FF, b2 + (size_t)i * E, h,
        g2 + (size_t)i * E, be2 + (size_t)i * E, hb, E, FF);
  }

  // fp32 head
  gemm64f<true,true,false><<<dim3(E/64, ROWS/64), 256, 0, stream>>>(
      h, m3w1, m3b1, t1f, nullptr, E, E);
  final_r_kernel<<<ROWS, 256, 0, stream>>>(t1f, m3w2, m3b2, r);
  dist_kernel<<<ROWS, 512, 0, stream>>>(r, (float*)d_out);
}

// Round 7
// 816.693 us; speedup vs baseline: 1.0556x; 1.0556x over previous
//
#include <hip/hip_runtime.h>
#include <math.h>

constexpr int Bn = 8, NZ = 16, Ln = 512;
constexpr int E = 256, DM = 512, NH = 16, HD = 32;
constexpr int FF = 1024, NL = 8, E1D = 32, PDIM = 64, PMAX = 24;
constexpr int ROWS = Bn * Ln;                       // 4096
constexpr float QSCALE = 0.04419417382415922f;      // 1/sqrt(512)

typedef __attribute__((ext_vector_type(8))) short bf16x8;
typedef __attribute__((ext_vector_type(4))) float floatx4;

__device__ inline unsigned short f2b(float f) {
  union { float f; unsigned u; } v; v.f = f;
  unsigned r = (v.u + 0x7FFF + ((v.u >> 16) & 1)) >> 16;
  return (unsigned short)r;
}
__device__ inline float b2f(unsigned short u) {
  union { unsigned u; float f; } v; v.u = ((unsigned)u) << 16; return v.f;
}

// async global->LDS DMA, 16B per lane; LDS dest is wave-uniform base + lane*16
// (m104 semantics). Compiler drains vmcnt(0) at __syncthreads -> data visible.
__device__ inline void gll16(const void* g, void* l) {
  __builtin_amdgcn_global_load_lds(
      (const __attribute__((address_space(1))) void*)g,
      (__attribute__((address_space(3))) void*)l, 16, 0, 0);
}

// ---------------------------------------------------------------------------
// batched Wq/Wk/Wv fp32 [l][E][DM] -> bf16 qkvT [l][3*DM][E]
// ---------------------------------------------------------------------------
__global__ __launch_bounds__(256) void transpose_qkv(
    const float* __restrict__ Wq, const float* __restrict__ Wk,
    const float* __restrict__ Wv, unsigned short* __restrict__ qkvT)
{
  __shared__ float t[32][33];
  int zb = blockIdx.z;
  int which = zb / NL, l = zb % NL;
  const float* s = (which == 0 ? Wq : which == 1 ? Wk : Wv) + (size_t)l * E * DM;
  unsigned short* d = qkvT + (size_t)l * 3 * DM * E + (size_t)which * DM * E;
  int c0 = blockIdx.x * 32, r0 = blockIdx.y * 32;
  int tx = threadIdx.x & 31, ty = threadIdx.x >> 5;
  #pragma unroll
  for (int i = 0; i < 4; ++i)
    t[ty + i * 8][tx] = s[(size_t)(r0 + ty + i * 8) * DM + c0 + tx];
  __syncthreads();
  #pragma unroll
  for (int i = 0; i < 4; ++i)
    d[(size_t)(c0 + ty + i * 8) * E + r0 + tx] = f2b(t[tx][ty + i * 8]);
}

// ---------------------------------------------------------------------------
// generic fp32 [l][R][C] -> bf16 [l][C][R]
// ---------------------------------------------------------------------------
__global__ __launch_bounds__(256) void transpose_bf16(
    const float* __restrict__ src, unsigned short* __restrict__ dst,
    int R, int C, size_t sls, size_t dls)
{
  __shared__ float t[32][33];
  int l = blockIdx.z;
  int c0 = blockIdx.x * 32, r0 = blockIdx.y * 32;
  int tx = threadIdx.x & 31, ty = threadIdx.x >> 5;
  const float* s = src + (size_t)l * sls;
  unsigned short* d = dst + (size_t)l * dls;
  #pragma unroll
  for (int i = 0; i < 4; ++i)
    t[ty + i * 8][tx] = s[(size_t)(r0 + ty + i * 8) * C + c0 + tx];
  __syncthreads();
  #pragma unroll
  for (int i = 0; i < 4; ++i)
    d[(size_t)(c0 + ty + i * 8) * R + r0 + tx] = f2b(t[tx][ty + i * 8]);
}

// ---------------------------------------------------------------------------
// embed stage 1: t0 = relu(z^T @ ex_w1 + b1) fp32; e_aa gather into umb
// ---------------------------------------------------------------------------
__global__ __launch_bounds__(256) void embed1_kernel(
    const float* __restrict__ z, const float* __restrict__ x,
    const float* __restrict__ aa,
    const float* __restrict__ w1, const float* __restrict__ b1,
    float* __restrict__ t0, unsigned short* __restrict__ umb)
{
  int row = blockIdx.x;
  int b = row >> 9, l = row & (Ln - 1);
  int t = threadIdx.x;
  __shared__ float zs[NZ];
  __shared__ int am_s;
  if (t < NZ) zs[t] = z[((size_t)b * NZ + t) * Ln + l];
  if (t == 0) {
    const float* xp = x + (size_t)b * 20 * Ln + l;
    int am = 0; float bv = xp[0];
    for (int c = 1; c < 20; ++c) { float vv = xp[(size_t)c * Ln]; if (vv > bv) { bv = vv; am = c; } }
    am_s = am;
  }
  __syncthreads();
  float a1 = b1[t];
  #pragma unroll
  for (int nz = 0; nz < NZ; ++nz) a1 += zs[nz] * w1[nz * E + t];
  t0[(size_t)row * E + t] = fmaxf(a1, 0.f);
  if (t < E1D) umb[(size_t)row * (E + E1D) + E + t] = f2b(aa[am_s * E1D + t]);
}

// ---------------------------------------------------------------------------
// pairwise-bias collapse: 49 bins per (layer, head)
// ---------------------------------------------------------------------------
__global__ __launch_bounds__(256) void bias_kernel(
    const float* __restrict__ pos, const float* __restrict__ W2d,
    const float* __restrict__ b2d, float* __restrict__ bias49)
{
  int layer = blockIdx.x;
  for (int idx = threadIdx.x; idx < NH * 49; idx += 256) {
    int hh = idx / 49, bin = idx % 49;
    float acc = b2d[layer * NH + hh];
    for (int p = 0; p < PDIM; ++p)
      acc += pos[bin * PDIM + p] * W2d[((size_t)layer * PDIM + p) * NH + hh];
    bias49[(size_t)layer * NH * 49 + hh * 49 + bin] = acc;
  }
}

// ---------------------------------------------------------------------------
// bf16 MFMA GEMM. BK in {32, 128}. (R17-proven, unchanged)
// ---------------------------------------------------------------------------
template<int BM, int BN, int BK, bool BIAS, bool RELU, bool OUTBF16, bool QKV>
__global__ __launch_bounds__(256) void gemm_mfma(
    const unsigned short* __restrict__ A, const unsigned short* __restrict__ Bt,
    const float* __restrict__ bias,
    float* __restrict__ Cf, unsigned short* __restrict__ Cb, int N, int K)
{
  constexpr int MT = BM / 32, NT = BN / 32;
  __shared__ __align__(16) unsigned short As[BM][BK];
  __shared__ __align__(16) unsigned short Bs[BN][BK];
  const int tid = threadIdx.x;
  const int wave = tid >> 6, ln = tid & 63;
  const int quad = ln >> 4, l16 = ln & 15;
  const int wm = wave >> 1, wn = wave & 1;
  const int m0 = blockIdx.y * BM, n0 = blockIdx.x * BN;

  floatx4 acc[MT][NT] = {};

  if constexpr (BK == 32) {
    // 16 rows per wave-issue, 4x16B chunks per 64B row
    const int lrow = ln >> 2, chunk = ln & 3;
    const int schunk = chunk ^ ((lrow >> 1) & 3);
    const unsigned short* aSrc = A + (size_t)(m0 + wave * 16 + lrow) * K + schunk * 8;
    const unsigned short* bSrc = Bt + (size_t)(n0 + wave * 16 + lrow) * K + schunk * 8;
    const int rkey = (l16 >> 1) & 3;

    for (int kb = 0; kb < K; kb += 32) {
      __syncthreads();
      #pragma unroll
      for (int it = 0; it < BM / 64; ++it)
        gll16(aSrc + (size_t)it * 64 * K + kb, &As[it * 64 + wave * 16][0]);
      #pragma unroll
      for (int it = 0; it < BN / 64; ++it)
        gll16(bSrc + (size_t)it * 64 * K + kb, &Bs[it * 64 + wave * 16][0]);
      __syncthreads();
      bf16x8 af[MT], bfr[NT];
      #pragma unroll
      for (int i = 0; i < MT; ++i)
        af[i] = *(const bf16x8*)&As[wm * (BM / 2) + i * 16 + l16][(quad ^ rkey) * 8];
      #pragma unroll
      for (int j = 0; j < NT; ++j)
        bfr[j] = *(const bf16x8*)&Bs[wn * (BN / 2) + j * 16 + l16][(quad ^ rkey) * 8];
      #pragma unroll
      for (int i = 0; i < MT; ++i)
        #pragma unroll
        for (int j = 0; j < NT; ++j)
          acc[i][j] = __builtin_amdgcn_mfma_f32_16x16x32_bf16(af[i], bfr[j], acc[i][j], 0, 0, 0);
    }
  } else {
    // BK=128: 4 rows per wave-issue, 16x16B chunks per 256B row.
    const int lrow = ln >> 4, chunk = ln & 15;
    const int key = wave * 4 + lrow;              // < 16
    const int schunk = chunk ^ key;
    const unsigned short* aSrc = A + (size_t)(m0 + key) * K + schunk * 8;
    const unsigned short* bSrc = Bt + (size_t)(n0 + key) * K + schunk * 8;

    for (int kb = 0; kb < K; kb += 128) {
      __syncthreads();
      #pragma unroll
      for (int it = 0; it < BM / 16; ++it)
        gll16(aSrc + (size_t)(it * 16) * K + kb, &As[it * 16 + wave * 4][0]);
      #pragma unroll
      for (int it = 0; it < BN / 16; ++it)
        gll16(bSrc + (size_t)(it * 16) * K + kb, &Bs[it * 16 + wave * 4][0]);
      __syncthreads();
      #pragma unroll
      for (int kc = 0; kc < 4; ++kc) {
        bf16x8 af[MT], bfr[NT];
        #pragma unroll
        for (int i = 0; i < MT; ++i)
          af[i] = *(const bf16x8*)&As[wm * (BM / 2) + i * 16 + l16][(((kc * 4 + quad) ^ l16) * 8)];
        #pragma unroll
        for (int j = 0; j < NT; ++j)
          bfr[j] = *(const bf16x8*)&Bs[wn * (BN / 2) + j * 16 + l16][(((kc * 4 + quad) ^ l16) * 8)];
        #pragma unroll
        for (int i = 0; i < MT; ++i)
          #pragma unroll
          for (int j = 0; j < NT; ++j)
            acc[i][j] = __builtin_amdgcn_mfma_f32_16x16x32_bf16(af[i], bfr[j], acc[i][j], 0, 0, 0);
      }
    }
  }

  #pragma unroll
  for (int i = 0; i < MT; ++i)
    #pragma unroll
    for (int j = 0; j < NT; ++j) {
      int col = n0 + wn * (BN / 2) + j * 16 + l16;
      float bv = BIAS ? bias[col] : 0.f;
      float sc = QKV ? (col < 512 ? QSCALE : 1.f) : 1.f;
      #pragma unroll
      for (int r = 0; r < 4; ++r) {
        int rowg = m0 + wm * (BM / 2) + i * 16 + quad * 4 + r;
        float v = acc[i][j][r] * sc + bv;
        if (RELU) v = fmaxf(v, 0.f);
        if (OUTBF16) Cb[(size_t)rowg * N + col] = f2b(v);
        else Cf[(size_t)rowg * N + col] = v;
      }
    }
}

// ---------------------------------------------------------------------------
// Fused GEMM(+bias+resid) + LayerNorm, N = 256. (R17-proven, unchanged)
// ---------------------------------------------------------------------------
__global__ __launch_bounds__(256) void gemm_ln(
    const unsigned short* __restrict__ A, const unsigned short* __restrict__ Bt,
    const float* __restrict__ bias, float* __restrict__ h,
    const float* __restrict__ g, const float* __restrict__ be,
    unsigned short* __restrict__ outb, int bstride, int K)
{
  __shared__ __align__(16) unsigned short As[16][128];
  __shared__ __align__(16) unsigned short Bs[256][128];
  __shared__ __align__(16) float vtile[16][260];   // +4 pad: scatter 2-way max
  const int tid = threadIdx.x;
  const int w = tid >> 6, ln = tid & 63;
  const int quad = ln >> 4, l16 = ln & 15;
  const int m0 = blockIdx.x * 16;
  const int lrow = ln >> 4, chunk = ln & 15;
  const int key = w * 4 + lrow;                   // row & 15
  const int schunk = chunk ^ key;
  const unsigned short* aSrc = A + (size_t)(m0 + key) * K + schunk * 8;
  const unsigned short* bSrc = Bt + (size_t)key * K + schunk * 8;

  floatx4 acc[4] = {};

  for (int kb = 0; kb < K; kb += 128) {
    __syncthreads();
    gll16(aSrc + kb, &As[w * 4][0]);
    #pragma unroll
    for (int it = 0; it < 16; ++it)
      gll16(bSrc + (size_t)(it * 16) * K + kb, &Bs[it * 16 + w * 4][0]);
    __syncthreads();
    #pragma unroll
    for (int kc = 0; kc < 4; ++kc) {
      bf16x8 af = *(const bf16x8*)&As[l16][(((kc * 4 + quad) ^ l16) * 8)];
      #pragma unroll
      for (int nt = 0; nt < 4; ++nt) {
        bf16x8 bf = *(const bf16x8*)&Bs[w * 64 + nt * 16 + l16][(((kc * 4 + quad) ^ l16) * 8)];
        acc[nt] = __builtin_amdgcn_mfma_f32_16x16x32_bf16(af, bf, acc[nt], 0, 0, 0);
      }
    }
  }

  // v = (acc + bias) + resid — same op order as old gemm_n256 epilogue
  #pragma unroll
  for (int nt = 0; nt < 4; ++nt) {
    int col = w * 64 + nt * 16 + l16;
    float bv = bias[col];
    #pragma unroll
    for (int r = 0; r < 4; ++r) {
      int row = quad * 4 + r;
      vtile[row][col] = acc[nt][r] + bv + h[(size_t)(m0 + row) * E + col];
    }
  }
  __syncthreads();

  // LN phase — bitwise replica of ln_kernel (wave-per-row, float4 lanes)
  const int c0 = ln * 4;
  #pragma unroll
  for (int rr = 0; rr < 4; ++rr) {
    const int lr = w * 4 + rr;
    float4 v = *(const float4*)&vtile[lr][c0];
    float s = v.x + v.y + v.z + v.w;
    float s2 = v.x * v.x + v.y * v.y + v.z * v.z + v.w * v.w;
    #pragma unroll
    for (int off = 1; off < 64; off <<= 1) {
      s += __shfl_xor(s, off, 64);
      s2 += __shfl_xor(s2, off, 64);
    }
    const float mean = s * (1.f / E);
    const float rstd = rsqrtf(s2 * (1.f / E) - mean * mean + 1e-5f);
    const float4 gv = *(const float4*)(g + c0);
    const float4 bv = *(const float4*)(be + c0);
    float4 y;
    y.x = (v.x - mean) * rstd * gv.x + bv.x;
    y.y = (v.y - mean) * rstd * gv.y + bv.y;
    y.z = (v.z - mean) * rstd * gv.z + bv.z;
    y.w = (v.w - mean) * rstd * gv.w + bv.w;
    const size_t row = (size_t)(m0 + lr);
    *(float4*)(h + row * E + c0) = y;
    ushort4 yb;
    yb.x = f2b(y.x); yb.y = f2b(y.y); yb.z = f2b(y.z); yb.w = f2b(y.w);
    *(ushort4*)(outb + row * (size_t)bstride + c0) = yb;
  }
}

// ---------------------------------------------------------------------------
// MFMA flash attention. R19: QBLK=64 / 1024 blocks (R17's proven grid —
// the parallelism R18 wrongly gave up) + K/V double-buffer with ONE
// barrier per j-tile and prefetch issued AFTER the barrier (so the
// barrier's vmcnt(0) drain does NOT swallow it — R13's mistake; loads
// fly under the ~2000cy compute phase and are waited only at the next
// iteration's LDS write). Hazard: write(jt,buf[jt&1]) conflicts only
// with compute(jt-2) reads, complete before barrier(jt-1). Compute
// sequence per q-row identical to R17 -> bitwise-identical output.
// ---------------------------------------------------------------------------
__global__ __launch_bounds__(256) void attn_kernel(
    const unsigned short* __restrict__ qkv, const float* __restrict__ bias49,
    unsigned short* __restrict__ o)
{
  const int i0 = blockIdx.x * 64;
  const int bh = blockIdx.y;
  const int b = bh >> 4, hh = bh & 15;
  const int tid = threadIdx.x;
  const int wave = tid >> 6, ln = tid & 63;
  const int quad = ln >> 4, l16 = ln & 15;

  __shared__ __align__(16) unsigned short Kt[2][64][40];
  __shared__ __align__(16) unsigned short Vt[2][32][72];
  __shared__ __align__(16) unsigned short Pw[4][2][16][72];
  __shared__ float bsh[49];

  if (tid < 49) bsh[tid] = bias49[hh * 49 + tid];

  const unsigned short* qkvb = qkv + (size_t)b * Ln * 1536;

  const int qrow = i0 + wave * 16 + l16;
  const bf16x8 qf = *(const bf16x8*)(qkvb + (size_t)qrow * 1536 + hh * 32 + quad * 8);

  float m[4], l[4];
  #pragma unroll
  for (int r = 0; r < 4; ++r) { m[r] = -1e30f; l[r] = 0.f; }
  floatx4 acc_o[2] = {};

  const int krow = tid >> 2, kch = (tid & 3) * 8;
  const int vkey = tid & 63, vch = (tid >> 6) * 8;
  const unsigned short* kp = qkvb + (size_t)krow * 1536 + 512 + hh * 32 + kch;
  const unsigned short* vp = qkvb + (size_t)vkey * 1536 + 1024 + hh * 32 + vch;

  float4 kreg = *(const float4*)kp;
  bf16x8 vreg = *(const bf16x8*)vp;

  for (int jt = 0; jt < 8; ++jt) {
    const int j0 = jt * 64;
    const int cur = jt & 1;
    *(float4*)&Kt[cur][krow][kch] = kreg;
    #pragma unroll
    for (int i = 0; i < 8; ++i) Vt[cur][vch + i][vkey] = (unsigned short)vreg[i];
    __syncthreads();
    if (jt < 7) {   // AFTER barrier: latency hides under this tile's compute
      kreg = *(const float4*)(kp + (size_t)(j0 + 64) * 1536);
      vreg = *(const bf16x8*)(vp + (size_t)(j0 + 64) * 1536);
    }

    floatx4 s4[4];
    #pragma unroll
    for (int t = 0; t < 4; ++t) {
      bf16x8 kf = *(const bf16x8*)&Kt[cur][16 * t + l16][quad * 8];
      s4[t] = __builtin_amdgcn_mfma_f32_16x16x32_bf16(qf, kf, (floatx4){0.f, 0.f, 0.f, 0.f}, 0, 0, 0);
    }
    const int relmin = j0 - (i0 + 63), relmax = j0 + 63 - i0;
    if (relmin >= PMAX) {
      float bc = bsh[48];
      #pragma unroll
      for (int t = 0; t < 4; ++t)
        #pragma unroll
        for (int r = 0; r < 4; ++r) s4[t][r] += bc;
    } else if (relmax <= -PMAX) {
      float bc = bsh[0];
      #pragma unroll
      for (int t = 0; t < 4; ++t)
        #pragma unroll
        for (int r = 0; r < 4; ++r) s4[t][r] += bc;
    } else {
      const int base_rel = (j0 + l16) - (i0 + wave * 16 + quad * 4);
      #pragma unroll
      for (int t = 0; t < 4; ++t)
        #pragma unroll
        for (int r = 0; r < 4; ++r) {
          int rel = base_rel + 16 * t - r;
          rel = rel < -PMAX ? -PMAX : (rel > PMAX ? PMAX : rel);
          s4[t][r] += bsh[rel + PMAX];
        }
    }

    float mloc[4], alpha[4], psum[4];
    #pragma unroll
    for (int r = 0; r < 4; ++r) {
      mloc[r] = fmaxf(fmaxf(s4[0][r], s4[1][r]), fmaxf(s4[2][r], s4[3][r]));
      #pragma unroll
      for (int off = 1; off < 16; off <<= 1)
        mloc[r] = fmaxf(mloc[r], __shfl_xor(mloc[r], off, 64));
      float mnew = fmaxf(m[r], mloc[r]);
      alpha[r] = __expf(m[r] - mnew);
      m[r] = mnew;
      psum[r] = 0.f;
    }
    #pragma unroll
    for (int t = 0; t < 4; ++t)
      #pragma unroll
      for (int r = 0; r < 4; ++r) {
        float p = __expf(s4[t][r] - m[r]);
        s4[t][r] = p;
        psum[r] += p;
      }
    #pragma unroll
    for (int r = 0; r < 4; ++r) {
      #pragma unroll
      for (int off = 1; off < 16; off <<= 1)
        psum[r] += __shfl_xor(psum[r], off, 64);
      l[r] = l[r] * alpha[r] + psum[r];
      acc_o[0][r] *= alpha[r];
      acc_o[1][r] *= alpha[r];
    }

    #pragma unroll
    for (int t = 0; t < 4; ++t)
      #pragma unroll
      for (int r = 0; r < 4; ++r) {
        float p = s4[t][r];
        unsigned short hi = f2b(p);
        unsigned short lo = f2b(p - b2f(hi));
        Pw[wave][0][quad * 4 + r][16 * t + l16] = hi;
        Pw[wave][1][quad * 4 + r][16 * t + l16] = lo;
      }

    #pragma unroll
    for (int kh = 0; kh < 2; ++kh) {
      bf16x8 phi = *(const bf16x8*)&Pw[wave][0][l16][kh * 32 + quad * 8];
      bf16x8 plo = *(const bf16x8*)&Pw[wave][1][l16][kh * 32 + quad * 8];
      #pragma unroll
      for (int nt = 0; nt < 2; ++nt) {
        bf16x8 vf = *(const bf16x8*)&Vt[cur][nt * 16 + l16][kh * 32 + quad * 8];
        acc_o[nt] = __builtin_amdgcn_mfma_f32_16x16x32_bf16(phi, vf, acc_o[nt], 0, 0, 0);
        acc_o[nt] = __builtin_amdgcn_mfma_f32_16x16x32_bf16(plo, vf, acc_o[nt], 0, 0, 0);
      }
    }
  }

  #pragma unroll
  for (int r = 0; r < 4; ++r) {
    float inv = 1.f / l[r];
    size_t rowg = (size_t)b * Ln + i0 + wave * 16 + quad * 4 + r;
    #pragma unroll
    for (int nt = 0; nt < 2; ++nt)
      o[rowg * 512 + hh * 32 + nt * 16 + l16] = f2b(acc_o[nt][r] * inv);
  }
}

// ---------------------------------------------------------------------------
// fp32 tiled GEMM: C = act(A@B + bias), optional bf16 mirror (embed2 / head)
// ---------------------------------------------------------------------------
template<bool RELU, bool BIAS, bool MIRROR>
__global__ __launch_bounds__(256) void gemm64f(
    const float* __restrict__ A, const float* __restrict__ B,
    const float* __restrict__ bias, float* __restrict__ C,
    unsigned short* __restrict__ mir, int N, int K)
{
  __shared__ __align__(16) float As[16][64];
  __shared__ __align__(16) float Bss[16][68];
  const int tid = threadIdx.x;
  const int tx = tid & 15, ty = tid >> 4;
  const int m0 = blockIdx.y * 64, n0 = blockIdx.x * 64;
  const int arow = tid >> 2, acol = (tid & 3) * 4;
  const int brow = tid >> 6, bcol = tid & 63;
  float acc[4][4] = {};
  for (int kb = 0; kb < K; kb += 16) {
    __syncthreads();
    float4 av = *(const float4*)(A + (size_t)(m0 + arow) * K + kb + acol);
    As[acol + 0][arow] = av.x; As[acol + 1][arow] = av.y;
    As[acol + 2][arow] = av.z; As[acol + 3][arow] = av.w;
    #pragma unroll
    for (int kk = 0; kk < 4; ++kk)
      Bss[brow + kk * 4][bcol] = B[(size_t)(kb + brow + kk * 4) * N + n0 + bcol];
    __syncthreads();
    #pragma unroll
    for (int k = 0; k < 16; ++k) {
      float4 a = *(const float4*)&As[k][4 * ty];
      float4 b = *(const float4*)&Bss[k][4 * tx];
      float av4[4] = {a.x, a.y, a.z, a.w};
      float bv4[4] = {b.x, b.y, b.z, b.w};
      #pragma unroll
      for (int ii = 0; ii < 4; ++ii)
        #pragma unroll
        for (int jj = 0; jj < 4; ++jj)
          acc[ii][jj] += av4[ii] * bv4[jj];
    }
  }
  #pragma unroll
  for (int ii = 0; ii < 4; ++ii) {
    size_t row = (size_t)m0 + 4 * ty + ii;
    int col = n0 + 4 * tx;
    float4 vv;
    vv.x = acc[ii][0]; vv.y = acc[ii][1]; vv.z = acc[ii][2]; vv.w = acc[ii][3];
    if (BIAS) {
      float4 bb = *(const float4*)(bias + col);
      vv.x += bb.x; vv.y += bb.y; vv.z += bb.z; vv.w += bb.w;
    }
    if (RELU) {
      vv.x = fmaxf(vv.x, 0.f); vv.y = fmaxf(vv.y, 0.f);
      vv.z = fmaxf(vv.z, 0.f); vv.w = fmaxf(vv.w, 0.f);
    }
    *(float4*)(C + row * N + col) = vv;
    if (MIRROR) {
      ushort4 mv;
      mv.x = f2b(vv.x); mv.y = f2b(vv.y); mv.z = f2b(vv.z); mv.w = f2b(vv.w);
      *(ushort4*)(mir + row * N + col) = mv;
    }
  }
}

__global__ __launch_bounds__(256) void final_r_kernel(
    const float* __restrict__ t1, const float* __restrict__ w2,
    const float* __restrict__ b2, float* __restrict__ r)
{
  int row = blockIdx.x, t = threadIdx.x;
  float xv = t1[(size_t)row * E + t];
  float p0 = xv * w2[t * 3 + 0];
  float p1 = xv * w2[t * 3 + 1];
  float p2 = xv * w2[t * 3 + 2];
  #pragma unroll
  for (int off = 32; off > 0; off >>= 1) {
    p0 += __shfl_down(p0, off, 64);
    p1 += __shfl_down(p1, off, 64);
    p2 += __shfl_down(p2, off, 64);
  }
  __shared__ float red[4][3];
  if ((t & 63) == 0) { int w = t >> 6; red[w][0] = p0; red[w][1] = p1; red[w][2] = p2; }
  __syncthreads();
  if (t < 3)
    r[(size_t)row * 3 + t] = red[0][t] + red[1][t] + red[2][t] + red[3][t] + b2[t];
}

__global__ __launch_bounds__(512) void dist_kernel(
    const float* __restrict__ r, float* __restrict__ out)
{
  int bi = blockIdx.x;
  int j = threadIdx.x;
  int b = bi >> 9;
  float x0 = r[(size_t)bi * 3 + 0];
  float y0 = r[(size_t)bi * 3 + 1];
  float z0 = r[(size_t)bi * 3 + 2];
  const float* rj = r + ((size_t)b * Ln + j) * 3;
  float dx = rj[0] - x0, dy = rj[1] - y0, dz = rj[2] - z0;
  out[(size_t)bi * Ln + j] = sqrtf(dx * dx + dy * dy + dz * dz + 1e-12f);
}

// ---------------------------------------------------------------------------
extern "C" void kernel_launch(void* const* d_in, const int* in_sizes, int n_in,
                              void* d_out, int out_size, void* d_ws, size_t ws_size,
                              hipStream_t stream)
{
  const float* z     = (const float*)d_in[0];
  const float* x     = (const float*)d_in[1];
  const float* pos   = (const float*)d_in[2];
  const float* aa    = (const float*)d_in[3];
  const float* ex_w1 = (const float*)d_in[4];
  const float* ex_b1 = (const float*)d_in[5];
  const float* ex_w2 = (const float*)d_in[6];
  const float* ex_b2 = (const float*)d_in[7];
  const float* Wq    = (const float*)d_in[8];
  const float* Wk    = (const float*)d_in[9];
  const float* Wv    = (const float*)d_in[10];
  const float* Wo    = (const float*)d_in[11];
  const float* bo    = (const float*)d_in[12];
  const float* W2d   = (const float*)d_in[13];
  const float* b2d   = (const float*)d_in[14];
  const float* W1    = (const float*)d_in[15];
  const float* b1    = (const float*)d_in[16];
  const float* W2    = (const float*)d_in[17];
  const float* b2    = (const float*)d_in[18];
  const float* g1    = (const float*)d_in[19];
  const float* be1   = (const float*)d_in[20];
  const float* g2    = (const float*)d_in[21];
  const float* be2   = (const float*)d_in[22];
  const float* m3w1  = (const float*)d_in[23];
  const float* m3b1  = (const float*)d_in[24];
  const float* m3w2  = (const float*)d_in[25];
  const float* m3b2  = (const float*)d_in[26];

  float* ws     = (float*)d_ws;
  float* h      = ws;                          // 4096*256
  float* t0     = h + (size_t)ROWS * E;        // 4096*256 (embed hidden / tmp)
  float* r      = t0 + (size_t)ROWS * E;       // 4096*3
  float* bias49 = r + (size_t)ROWS * 3;        // 8*16*49
  unsigned short* us = (unsigned short*)(bias49 + NL * NH * 49);
  unsigned short* hb   = us;                              // 4096*256
  unsigned short* umb  = hb  + (size_t)ROWS * E;          // 4096*288
  unsigned short* qkvb = umb + (size_t)ROWS * (E + E1D);  // 4096*1536
  unsigned short* ob   = qkvb + (size_t)ROWS * 3 * DM;    // 4096*512
  unsigned short* t1b  = ob  + (size_t)ROWS * DM;         // 4096*1024
  unsigned short* qkvT = t1b + (size_t)ROWS * FF;         // 8*1536*256
  unsigned short* WoT  = qkvT + (size_t)NL * 3 * DM * E;  // 8*256*512
  unsigned short* W1T  = WoT  + (size_t)NL * E * DM;      // 8*1024*288
  unsigned short* W2T  = W1T  + (size_t)NL * FF * (E+E1D);// 8*256*1024
  float* t1f = (float*)t1b;   // head scratch aliases t1b

  // ---- weight transpose+convert (4 launches) ----
  transpose_qkv<<<dim3(DM/32, E/32, 3*NL), 256, 0, stream>>>(Wq, Wk, Wv, qkvT);
  transpose_bf16<<<dim3(E/32, DM/32, NL), 256, 0, stream>>>(
      Wo, WoT, DM, E, (size_t)DM * E, (size_t)DM * E);
  transpose_bf16<<<dim3(FF/32, (E+E1D)/32, NL), 256, 0, stream>>>(
      W1, W1T, E + E1D, FF, (size_t)(E+E1D) * FF, (size_t)(E+E1D) * FF);
  transpose_bf16<<<dim3(E/32, FF/32, NL), 256, 0, stream>>>(
      W2, W2T, FF, E, (size_t)FF * E, (size_t)FF * E);

  embed1_kernel<<<ROWS, 256, 0, stream>>>(z, x, aa, ex_w1, ex_b1, t0, umb);
  gemm64f<false,true,true><<<dim3(E/64, ROWS/64), 256, 0, stream>>>(
      t0, ex_w2, ex_b2, h, hb, E, E);
  bias_kernel<<<NL, 256, 0, stream>>>(pos, W2d, b2d, bias49);

  for (int i = 0; i < NL; ++i) {
    // fused QKV: N=1536, 64x128 tiles, BK=128 -> 768 blocks (3/CU), 2 K-steps
    gemm_mfma<64,128,128,false,false,true,true><<<dim3(12, 64), 256, 0, stream>>>(
        hb, qkvT + (size_t)i * 3 * DM * E, nullptr, nullptr, qkvb, 3 * DM, E);
    // attention: QBLK=64 -> grid (8, 128) = 1024 blocks (R17 parallelism)
    attn_kernel<<<dim3(Ln/64, Bn*NH), 256, 0, stream>>>(
        qkvb, bias49 + (size_t)i * NH * 49, ob);
    // fused Wo + bias + resid + LN1 -> h, umb  (256 blocks, 4 K-steps)
    gemm_ln<<<ROWS/16, 256, 0, stream>>>(
        ob, WoT + (size_t)i * DM * E, bo + (size_t)i * E, h,
        g1 + (size_t)i * E, be1 + (size_t)i * E, umb, E + E1D, DM);
    // FF1 + bias + relu -> bf16 t1b  (64x64 tiles, BK=32 -> 1024 blocks, 4/CU)
    gemm_mfma<64,64,32,true,true,true,false><<<dim3(FF/64, ROWS/64), 256, 0, stream>>>(
        umb, W1T + (size_t)i * FF * (E+E1D), b1 + (size_t)i * FF, nullptr, t1b, FF, E + E1D);
    // fused FF2 + bias + resid + LN2 -> h, hb  (256 blocks, 8 K-steps)
    gemm_ln<<<ROWS/16, 256, 0, stream>>>(
        t1b, W2T + (size_t)i * E * FF, b2 + (size_t)i * E, h,
        g2 + (size_t)i * E, be2 + (size_t)i * E, hb, E, FF);
  }

  // fp32 head
  gemm64f<true,true,false><<<dim3(E/64, ROWS/64), 256, 0, stream>>>(
      h, m3w1, m3b1, t1f, nullptr, E, E);
  final_r_kernel<<<ROWS, 256, 0, stream>>>(t1f, m3w2, m3b2, r);
  dist_kernel<<<ROWS, 512, 0, stream>>>(r, (float*)d_out);
}

// Round 8
// 804.502 us; speedup vs baseline: 1.0716x; 1.0152x over previous
//
#include <hip/hip_runtime.h>
#include <math.h>

constexpr int Bn = 8, NZ = 16, Ln = 512;
constexpr int E = 256, DM = 512, NH = 16, HD = 32;
constexpr int FF = 1024, NL = 8, E1D = 32, PDIM = 64, PMAX = 24;
constexpr int ROWS = Bn * Ln;                       // 4096
constexpr float QSCALE = 0.04419417382415922f;      // 1/sqrt(512)

typedef __attribute__((ext_vector_type(8))) short bf16x8;
typedef __attribute__((ext_vector_type(4))) float floatx4;

__device__ inline unsigned short f2b(float f) {
  union { float f; unsigned u; } v; v.f = f;
  unsigned r = (v.u + 0x7FFF + ((v.u >> 16) & 1)) >> 16;
  return (unsigned short)r;
}
__device__ inline float b2f(unsigned short u) {
  union { unsigned u; float f; } v; v.u = ((unsigned)u) << 16; return v.f;
}

// async global->LDS DMA, 16B per lane; LDS dest is wave-uniform base + lane*16
// (m104 semantics). Compiler drains vmcnt(0) at __syncthreads -> data visible.
__device__ inline void gll16(const void* g, void* l) {
  __builtin_amdgcn_global_load_lds(
      (const __attribute__((address_space(1))) void*)g,
      (__attribute__((address_space(3))) void*)l, 16, 0, 0);
}

// ---------------------------------------------------------------------------
// batched Wq/Wk/Wv fp32 [l][E][DM] -> bf16 qkvT [l][3*DM][E]
// ---------------------------------------------------------------------------
__global__ __launch_bounds__(256) void transpose_qkv(
    const float* __restrict__ Wq, const float* __restrict__ Wk,
    const float* __restrict__ Wv, unsigned short* __restrict__ qkvT)
{
  __shared__ float t[32][33];
  int zb = blockIdx.z;
  int which = zb / NL, l = zb % NL;
  const float* s = (which == 0 ? Wq : which == 1 ? Wk : Wv) + (size_t)l * E * DM;
  unsigned short* d = qkvT + (size_t)l * 3 * DM * E + (size_t)which * DM * E;
  int c0 = blockIdx.x * 32, r0 = blockIdx.y * 32;
  int tx = threadIdx.x & 31, ty = threadIdx.x >> 5;
  #pragma unroll
  for (int i = 0; i < 4; ++i)
    t[ty + i * 8][tx] = s[(size_t)(r0 + ty + i * 8) * DM + c0 + tx];
  __syncthreads();
  #pragma unroll
  for (int i = 0; i < 4; ++i)
    d[(size_t)(c0 + ty + i * 8) * E + r0 + tx] = f2b(t[tx][ty + i * 8]);
}

// ---------------------------------------------------------------------------
// generic fp32 [l][R][C] -> bf16 [l][C][R]
// ---------------------------------------------------------------------------
__global__ __launch_bounds__(256) void transpose_bf16(
    const float* __restrict__ src, unsigned short* __restrict__ dst,
    int R, int C, size_t sls, size_t dls)
{
  __shared__ float t[32][33];
  int l = blockIdx.z;
  int c0 = blockIdx.x * 32, r0 = blockIdx.y * 32;
  int tx = threadIdx.x & 31, ty = threadIdx.x >> 5;
  const float* s = src + (size_t)l * sls;
  unsigned short* d = dst + (size_t)l * dls;
  #pragma unroll
  for (int i = 0; i < 4; ++i)
    t[ty + i * 8][tx] = s[(size_t)(r0 + ty + i * 8) * C + c0 + tx];
  __syncthreads();
  #pragma unroll
  for (int i = 0; i < 4; ++i)
    d[(size_t)(c0 + ty + i * 8) * R + r0 + tx] = f2b(t[tx][ty + i * 8]);
}

// ---------------------------------------------------------------------------
// embed stage 1: t0 = relu(z^T @ ex_w1 + b1) fp32; e_aa gather into umb
// ---------------------------------------------------------------------------
__global__ __launch_bounds__(256) void embed1_kernel(
    const float* __restrict__ z, const float* __restrict__ x,
    const float* __restrict__ aa,
    const float* __restrict__ w1, const float* __restrict__ b1,
    float* __restrict__ t0, unsigned short* __restrict__ umb)
{
  int row = blockIdx.x;
  int b = row >> 9, l = row & (Ln - 1);
  int t = threadIdx.x;
  __shared__ float zs[NZ];
  __shared__ int am_s;
  if (t < NZ) zs[t] = z[((size_t)b * NZ + t) * Ln + l];
  if (t == 0) {
    const float* xp = x + (size_t)b * 20 * Ln + l;
    int am = 0; float bv = xp[0];
    for (int c = 1; c < 20; ++c) { float vv = xp[(size_t)c * Ln]; if (vv > bv) { bv = vv; am = c; } }
    am_s = am;
  }
  __syncthreads();
  float a1 = b1[t];
  #pragma unroll
  for (int nz = 0; nz < NZ; ++nz) a1 += zs[nz] * w1[nz * E + t];
  t0[(size_t)row * E + t] = fmaxf(a1, 0.f);
  if (t < E1D) umb[(size_t)row * (E + E1D) + E + t] = f2b(aa[am_s * E1D + t]);
}

// ---------------------------------------------------------------------------
// pairwise-bias collapse: 49 bins per (layer, head)
// ---------------------------------------------------------------------------
__global__ __launch_bounds__(256) void bias_kernel(
    const float* __restrict__ pos, const float* __restrict__ W2d,
    const float* __restrict__ b2d, float* __restrict__ bias49)
{
  int layer = blockIdx.x;
  for (int idx = threadIdx.x; idx < NH * 49; idx += 256) {
    int hh = idx / 49, bin = idx % 49;
    float acc = b2d[layer * NH + hh];
    for (int p = 0; p < PDIM; ++p)
      acc += pos[bin * PDIM + p] * W2d[((size_t)layer * PDIM + p) * NH + hh];
    bias49[(size_t)layer * NH * 49 + hh * 49 + bin] = acc;
  }
}

// ---------------------------------------------------------------------------
// bf16 MFMA GEMM. BK in {32, 128}. (R17-proven, unchanged)
// ---------------------------------------------------------------------------
template<int BM, int BN, int BK, bool BIAS, bool RELU, bool OUTBF16, bool QKV>
__global__ __launch_bounds__(256) void gemm_mfma(
    const unsigned short* __restrict__ A, const unsigned short* __restrict__ Bt,
    const float* __restrict__ bias,
    float* __restrict__ Cf, unsigned short* __restrict__ Cb, int N, int K)
{
  constexpr int MT = BM / 32, NT = BN / 32;
  __shared__ __align__(16) unsigned short As[BM][BK];
  __shared__ __align__(16) unsigned short Bs[BN][BK];
  const int tid = threadIdx.x;
  const int wave = tid >> 6, ln = tid & 63;
  const int quad = ln >> 4, l16 = ln & 15;
  const int wm = wave >> 1, wn = wave & 1;
  const int m0 = blockIdx.y * BM, n0 = blockIdx.x * BN;

  floatx4 acc[MT][NT] = {};

  if constexpr (BK == 32) {
    // 16 rows per wave-issue, 4x16B chunks per 64B row
    const int lrow = ln >> 2, chunk = ln & 3;
    const int schunk = chunk ^ ((lrow >> 1) & 3);
    const unsigned short* aSrc = A + (size_t)(m0 + wave * 16 + lrow) * K + schunk * 8;
    const unsigned short* bSrc = Bt + (size_t)(n0 + wave * 16 + lrow) * K + schunk * 8;
    const int rkey = (l16 >> 1) & 3;

    for (int kb = 0; kb < K; kb += 32) {
      __syncthreads();
      #pragma unroll
      for (int it = 0; it < BM / 64; ++it)
        gll16(aSrc + (size_t)it * 64 * K + kb, &As[it * 64 + wave * 16][0]);
      #pragma unroll
      for (int it = 0; it < BN / 64; ++it)
        gll16(bSrc + (size_t)it * 64 * K + kb, &Bs[it * 64 + wave * 16][0]);
      __syncthreads();
      bf16x8 af[MT], bfr[NT];
      #pragma unroll
      for (int i = 0; i < MT; ++i)
        af[i] = *(const bf16x8*)&As[wm * (BM / 2) + i * 16 + l16][(quad ^ rkey) * 8];
      #pragma unroll
      for (int j = 0; j < NT; ++j)
        bfr[j] = *(const bf16x8*)&Bs[wn * (BN / 2) + j * 16 + l16][(quad ^ rkey) * 8];
      #pragma unroll
      for (int i = 0; i < MT; ++i)
        #pragma unroll
        for (int j = 0; j < NT; ++j)
          acc[i][j] = __builtin_amdgcn_mfma_f32_16x16x32_bf16(af[i], bfr[j], acc[i][j], 0, 0, 0);
    }
  } else {
    // BK=128: 4 rows per wave-issue, 16x16B chunks per 256B row.
    const int lrow = ln >> 4, chunk = ln & 15;
    const int key = wave * 4 + lrow;              // < 16
    const int schunk = chunk ^ key;
    const unsigned short* aSrc = A + (size_t)(m0 + key) * K + schunk * 8;
    const unsigned short* bSrc = Bt + (size_t)(n0 + key) * K + schunk * 8;

    for (int kb = 0; kb < K; kb += 128) {
      __syncthreads();
      #pragma unroll
      for (int it = 0; it < BM / 16; ++it)
        gll16(aSrc + (size_t)(it * 16) * K + kb, &As[it * 16 + wave * 4][0]);
      #pragma unroll
      for (int it = 0; it < BN / 16; ++it)
        gll16(bSrc + (size_t)(it * 16) * K + kb, &Bs[it * 16 + wave * 4][0]);
      __syncthreads();
      #pragma unroll
      for (int kc = 0; kc < 4; ++kc) {
        bf16x8 af[MT], bfr[NT];
        #pragma unroll
        for (int i = 0; i < MT; ++i)
          af[i] = *(const bf16x8*)&As[wm * (BM / 2) + i * 16 + l16][(((kc * 4 + quad) ^ l16) * 8)];
        #pragma unroll
        for (int j = 0; j < NT; ++j)
          bfr[j] = *(const bf16x8*)&Bs[wn * (BN / 2) + j * 16 + l16][(((kc * 4 + quad) ^ l16) * 8)];
        #pragma unroll
        for (int i = 0; i < MT; ++i)
          #pragma unroll
          for (int j = 0; j < NT; ++j)
            acc[i][j] = __builtin_amdgcn_mfma_f32_16x16x32_bf16(af[i], bfr[j], acc[i][j], 0, 0, 0);
      }
    }
  }

  #pragma unroll
  for (int i = 0; i < MT; ++i)
    #pragma unroll
    for (int j = 0; j < NT; ++j) {
      int col = n0 + wn * (BN / 2) + j * 16 + l16;
      float bv = BIAS ? bias[col] : 0.f;
      float sc = QKV ? (col < 512 ? QSCALE : 1.f) : 1.f;
      #pragma unroll
      for (int r = 0; r < 4; ++r) {
        int rowg = m0 + wm * (BM / 2) + i * 16 + quad * 4 + r;
        float v = acc[i][j][r] * sc + bv;
        if (RELU) v = fmaxf(v, 0.f);
        if (OUTBF16) Cb[(size_t)rowg * N + col] = f2b(v);
        else Cf[(size_t)rowg * N + col] = v;
      }
    }
}

// ---------------------------------------------------------------------------
// Fused GEMM(+bias+resid) + LayerNorm, N = 256. (R17-proven, unchanged)
// ---------------------------------------------------------------------------
__global__ __launch_bounds__(256) void gemm_ln(
    const unsigned short* __restrict__ A, const unsigned short* __restrict__ Bt,
    const float* __restrict__ bias, float* __restrict__ h,
    const float* __restrict__ g, const float* __restrict__ be,
    unsigned short* __restrict__ outb, int bstride, int K)
{
  __shared__ __align__(16) unsigned short As[16][128];
  __shared__ __align__(16) unsigned short Bs[256][128];
  __shared__ __align__(16) float vtile[16][260];   // +4 pad: scatter 2-way max
  const int tid = threadIdx.x;
  const int w = tid >> 6, ln = tid & 63;
  const int quad = ln >> 4, l16 = ln & 15;
  const int m0 = blockIdx.x * 16;
  const int lrow = ln >> 4, chunk = ln & 15;
  const int key = w * 4 + lrow;                   // row & 15
  const int schunk = chunk ^ key;
  const unsigned short* aSrc = A + (size_t)(m0 + key) * K + schunk * 8;
  const unsigned short* bSrc = Bt + (size_t)key * K + schunk * 8;

  floatx4 acc[4] = {};

  for (int kb = 0; kb < K; kb += 128) {
    __syncthreads();
    gll16(aSrc + kb, &As[w * 4][0]);
    #pragma unroll
    for (int it = 0; it < 16; ++it)
      gll16(bSrc + (size_t)(it * 16) * K + kb, &Bs[it * 16 + w * 4][0]);
    __syncthreads();
    #pragma unroll
    for (int kc = 0; kc < 4; ++kc) {
      bf16x8 af = *(const bf16x8*)&As[l16][(((kc * 4 + quad) ^ l16) * 8)];
      #pragma unroll
      for (int nt = 0; nt < 4; ++nt) {
        bf16x8 bf = *(const bf16x8*)&Bs[w * 64 + nt * 16 + l16][(((kc * 4 + quad) ^ l16) * 8)];
        acc[nt] = __builtin_amdgcn_mfma_f32_16x16x32_bf16(af, bf, acc[nt], 0, 0, 0);
      }
    }
  }

  // v = (acc + bias) + resid — same op order as old gemm_n256 epilogue
  #pragma unroll
  for (int nt = 0; nt < 4; ++nt) {
    int col = w * 64 + nt * 16 + l16;
    float bv = bias[col];
    #pragma unroll
    for (int r = 0; r < 4; ++r) {
      int row = quad * 4 + r;
      vtile[row][col] = acc[nt][r] + bv + h[(size_t)(m0 + row) * E + col];
    }
  }
  __syncthreads();

  // LN phase — bitwise replica of ln_kernel (wave-per-row, float4 lanes)
  const int c0 = ln * 4;
  #pragma unroll
  for (int rr = 0; rr < 4; ++rr) {
    const int lr = w * 4 + rr;
    float4 v = *(const float4*)&vtile[lr][c0];
    float s = v.x + v.y + v.z + v.w;
    float s2 = v.x * v.x + v.y * v.y + v.z * v.z + v.w * v.w;
    #pragma unroll
    for (int off = 1; off < 64; off <<= 1) {
      s += __shfl_xor(s, off, 64);
      s2 += __shfl_xor(s2, off, 64);
    }
    const float mean = s * (1.f / E);
    const float rstd = rsqrtf(s2 * (1.f / E) - mean * mean + 1e-5f);
    const float4 gv = *(const float4*)(g + c0);
    const float4 bv = *(const float4*)(be + c0);
    float4 y;
    y.x = (v.x - mean) * rstd * gv.x + bv.x;
    y.y = (v.y - mean) * rstd * gv.y + bv.y;
    y.z = (v.z - mean) * rstd * gv.z + bv.z;
    y.w = (v.w - mean) * rstd * gv.w + bv.w;
    const size_t row = (size_t)(m0 + lr);
    *(float4*)(h + row * E + c0) = y;
    ushort4 yb;
    yb.x = f2b(y.x); yb.y = f2b(y.y); yb.z = f2b(y.z); yb.w = f2b(y.w);
    *(ushort4*)(outb + row * (size_t)bstride + c0) = yb;
  }
}

// ---------------------------------------------------------------------------
// MFMA flash attention. R20: R19 body (dbuf, one barrier/tile, prefetch
// after barrier) + XCD-locality block remap (T1, bitwise-safe: index
// permutation only). 1D grid 1024; id = 64*gHigh + 8*k + gLow with
// bh = 8*gHigh + gLow, i0 = 64*k. All 8 q-tile blocks of one (b,head)
// group (and 16 groups) have id%8 == bh%8 -> same XCD under round-robin
// dispatch -> each 128KB K/V head-slice is fetched into that XCD's L2
// once (16 slices = 2MB < 4MB L2) and re-read as ~200cy L2 hits instead
// of ~900cy L3/HBM misses (R19 FETCH 35MB at 0.9 TB/s was this miss
// traffic). Compute sequence untouched -> bitwise-identical output.
// ---------------------------------------------------------------------------
__global__ __launch_bounds__(256) void attn_kernel(
    const unsigned short* __restrict__ qkv, const float* __restrict__ bias49,
    unsigned short* __restrict__ o)
{
  const int id = blockIdx.x;
  const int bh = ((id >> 6) << 3) | (id & 7);
  const int i0 = ((id >> 3) & 7) * 64;
  const int b = bh >> 4, hh = bh & 15;
  const int tid = threadIdx.x;
  const int wave = tid >> 6, ln = tid & 63;
  const int quad = ln >> 4, l16 = ln & 15;

  __shared__ __align__(16) unsigned short Kt[2][64][40];
  __shared__ __align__(16) unsigned short Vt[2][32][72];
  __shared__ __align__(16) unsigned short Pw[4][2][16][72];
  __shared__ float bsh[49];

  if (tid < 49) bsh[tid] = bias49[hh * 49 + tid];

  const unsigned short* qkvb = qkv + (size_t)b * Ln * 1536;

  const int qrow = i0 + wave * 16 + l16;
  const bf16x8 qf = *(const bf16x8*)(qkvb + (size_t)qrow * 1536 + hh * 32 + quad * 8);

  float m[4], l[4];
  #pragma unroll
  for (int r = 0; r < 4; ++r) { m[r] = -1e30f; l[r] = 0.f; }
  floatx4 acc_o[2] = {};

  const int krow = tid >> 2, kch = (tid & 3) * 8;
  const int vkey = tid & 63, vch = (tid >> 6) * 8;
  const unsigned short* kp = qkvb + (size_t)krow * 1536 + 512 + hh * 32 + kch;
  const unsigned short* vp = qkvb + (size_t)vkey * 1536 + 1024 + hh * 32 + vch;

  float4 kreg = *(const float4*)kp;
  bf16x8 vreg = *(const bf16x8*)vp;

  for (int jt = 0; jt < 8; ++jt) {
    const int j0 = jt * 64;
    const int cur = jt & 1;
    *(float4*)&Kt[cur][krow][kch] = kreg;
    #pragma unroll
    for (int i = 0; i < 8; ++i) Vt[cur][vch + i][vkey] = (unsigned short)vreg[i];
    __syncthreads();
    if (jt < 7) {   // AFTER barrier: latency hides under this tile's compute
      kreg = *(const float4*)(kp + (size_t)(j0 + 64) * 1536);
      vreg = *(const bf16x8*)(vp + (size_t)(j0 + 64) * 1536);
    }

    floatx4 s4[4];
    #pragma unroll
    for (int t = 0; t < 4; ++t) {
      bf16x8 kf = *(const bf16x8*)&Kt[cur][16 * t + l16][quad * 8];
      s4[t] = __builtin_amdgcn_mfma_f32_16x16x32_bf16(qf, kf, (floatx4){0.f, 0.f, 0.f, 0.f}, 0, 0, 0);
    }
    const int relmin = j0 - (i0 + 63), relmax = j0 + 63 - i0;
    if (relmin >= PMAX) {
      float bc = bsh[48];
      #pragma unroll
      for (int t = 0; t < 4; ++t)
        #pragma unroll
        for (int r = 0; r < 4; ++r) s4[t][r] += bc;
    } else if (relmax <= -PMAX) {
      float bc = bsh[0];
      #pragma unroll
      for (int t = 0; t < 4; ++t)
        #pragma unroll
        for (int r = 0; r < 4; ++r) s4[t][r] += bc;
    } else {
      const int base_rel = (j0 + l16) - (i0 + wave * 16 + quad * 4);
      #pragma unroll
      for (int t = 0; t < 4; ++t)
        #pragma unroll
        for (int r = 0; r < 4; ++r) {
          int rel = base_rel + 16 * t - r;
          rel = rel < -PMAX ? -PMAX : (rel > PMAX ? PMAX : rel);
          s4[t][r] += bsh[rel + PMAX];
        }
    }

    float mloc[4], alpha[4], psum[4];
    #pragma unroll
    for (int r = 0; r < 4; ++r) {
      mloc[r] = fmaxf(fmaxf(s4[0][r], s4[1][r]), fmaxf(s4[2][r], s4[3][r]));
      #pragma unroll
      for (int off = 1; off < 16; off <<= 1)
        mloc[r] = fmaxf(mloc[r], __shfl_xor(mloc[r], off, 64));
      float mnew = fmaxf(m[r], mloc[r]);
      alpha[r] = __expf(m[r] - mnew);
      m[r] = mnew;
      psum[r] = 0.f;
    }
    #pragma unroll
    for (int t = 0; t < 4; ++t)
      #pragma unroll
      for (int r = 0; r < 4; ++r) {
        float p = __expf(s4[t][r] - m[r]);
        s4[t][r] = p;
        psum[r] += p;
      }
    #pragma unroll
    for (int r = 0; r < 4; ++r) {
      #pragma unroll
      for (int off = 1; off < 16; off <<= 1)
        psum[r] += __shfl_xor(psum[r], off, 64);
      l[r] = l[r] * alpha[r] + psum[r];
      acc_o[0][r] *= alpha[r];
      acc_o[1][r] *= alpha[r];
    }

    #pragma unroll
    for (int t = 0; t < 4; ++t)
      #pragma unroll
      for (int r = 0; r < 4; ++r) {
        float p = s4[t][r];
        unsigned short hi = f2b(p);
        unsigned short lo = f2b(p - b2f(hi));
        Pw[wave][0][quad * 4 + r][16 * t + l16] = hi;
        Pw[wave][1][quad * 4 + r][16 * t + l16] = lo;
      }

    #pragma unroll
    for (int kh = 0; kh < 2; ++kh) {
      bf16x8 phi = *(const bf16x8*)&Pw[wave][0][l16][kh * 32 + quad * 8];
      bf16x8 plo = *(const bf16x8*)&Pw[wave][1][l16][kh * 32 + quad * 8];
      #pragma unroll
      for (int nt = 0; nt < 2; ++nt) {
        bf16x8 vf = *(const bf16x8*)&Vt[cur][nt * 16 + l16][kh * 32 + quad * 8];
        acc_o[nt] = __builtin_amdgcn_mfma_f32_16x16x32_bf16(phi, vf, acc_o[nt], 0, 0, 0);
        acc_o[nt] = __builtin_amdgcn_mfma_f32_16x16x32_bf16(plo, vf, acc_o[nt], 0, 0, 0);
      }
    }
  }

  #pragma unroll
  for (int r = 0; r < 4; ++r) {
    float inv = 1.f / l[r];
    size_t rowg = (size_t)b * Ln + i0 + wave * 16 + quad * 4 + r;
    #pragma unroll
    for (int nt = 0; nt < 2; ++nt)
      o[rowg * 512 + hh * 32 + nt * 16 + l16] = f2b(acc_o[nt][r] * inv);
  }
}

// ---------------------------------------------------------------------------
// fp32 tiled GEMM: C = act(A@B + bias), optional bf16 mirror (embed2 / head)
// ---------------------------------------------------------------------------
template<bool RELU, bool BIAS, bool MIRROR>
__global__ __launch_bounds__(256) void gemm64f(
    const float* __restrict__ A, const float* __restrict__ B,
    const float* __restrict__ bias, float* __restrict__ C,
    unsigned short* __restrict__ mir, int N, int K)
{
  __shared__ __align__(16) float As[16][64];
  __shared__ __align__(16) float Bss[16][68];
  const int tid = threadIdx.x;
  const int tx = tid & 15, ty = tid >> 4;
  const int m0 = blockIdx.y * 64, n0 = blockIdx.x * 64;
  const int arow = tid >> 2, acol = (tid & 3) * 4;
  const int brow = tid >> 6, bcol = tid & 63;
  float acc[4][4] = {};
  for (int kb = 0; kb < K; kb += 16) {
    __syncthreads();
    float4 av = *(const float4*)(A + (size_t)(m0 + arow) * K + kb + acol);
    As[acol + 0][arow] = av.x; As[acol + 1][arow] = av.y;
    As[acol + 2][arow] = av.z; As[acol + 3][arow] = av.w;
    #pragma unroll
    for (int kk = 0; kk < 4; ++kk)
      Bss[brow + kk * 4][bcol] = B[(size_t)(kb + brow + kk * 4) * N + n0 + bcol];
    __syncthreads();
    #pragma unroll
    for (int k = 0; k < 16; ++k) {
      float4 a = *(const float4*)&As[k][4 * ty];
      float4 b = *(const float4*)&Bss[k][4 * tx];
      float av4[4] = {a.x, a.y, a.z, a.w};
      float bv4[4] = {b.x, b.y, b.z, b.w};
      #pragma unroll
      for (int ii = 0; ii < 4; ++ii)
        #pragma unroll
        for (int jj = 0; jj < 4; ++jj)
          acc[ii][jj] += av4[ii] * bv4[jj];
    }
  }
  #pragma unroll
  for (int ii = 0; ii < 4; ++ii) {
    size_t row = (size_t)m0 + 4 * ty + ii;
    int col = n0 + 4 * tx;
    float4 vv;
    vv.x = acc[ii][0]; vv.y = acc[ii][1]; vv.z = acc[ii][2]; vv.w = acc[ii][3];
    if (BIAS) {
      float4 bb = *(const float4*)(bias + col);
      vv.x += bb.x; vv.y += bb.y; vv.z += bb.z; vv.w += bb.w;
    }
    if (RELU) {
      vv.x = fmaxf(vv.x, 0.f); vv.y = fmaxf(vv.y, 0.f);
      vv.z = fmaxf(vv.z, 0.f); vv.w = fmaxf(vv.w, 0.f);
    }
    *(float4*)(C + row * N + col) = vv;
    if (MIRROR) {
      ushort4 mv;
      mv.x = f2b(vv.x); mv.y = f2b(vv.y); mv.z = f2b(vv.z); mv.w = f2b(vv.w);
      *(ushort4*)(mir + row * N + col) = mv;
    }
  }
}

__global__ __launch_bounds__(256) void final_r_kernel(
    const float* __restrict__ t1, const float* __restrict__ w2,
    const float* __restrict__ b2, float* __restrict__ r)
{
  int row = blockIdx.x, t = threadIdx.x;
  float xv = t1[(size_t)row * E + t];
  float p0 = xv * w2[t * 3 + 0];
  float p1 = xv * w2[t * 3 + 1];
  float p2 = xv * w2[t * 3 + 2];
  #pragma unroll
  for (int off = 32; off > 0; off >>= 1) {
    p0 += __shfl_down(p0, off, 64);
    p1 += __shfl_down(p1, off, 64);
    p2 += __shfl_down(p2, off, 64);
  }
  __shared__ float red[4][3];
  if ((t & 63) == 0) { int w = t >> 6; red[w][0] = p0; red[w][1] = p1; red[w][2] = p2; }
  __syncthreads();
  if (t < 3)
    r[(size_t)row * 3 + t] = red[0][t] + red[1][t] + red[2][t] + red[3][t] + b2[t];
}

__global__ __launch_bounds__(512) void dist_kernel(
    const float* __restrict__ r, float* __restrict__ out)
{
  int bi = blockIdx.x;
  int j = threadIdx.x;
  int b = bi >> 9;
  float x0 = r[(size_t)bi * 3 + 0];
  float y0 = r[(size_t)bi * 3 + 1];
  float z0 = r[(size_t)bi * 3 + 2];
  const float* rj = r + ((size_t)b * Ln + j) * 3;
  float dx = rj[0] - x0, dy = rj[1] - y0, dz = rj[2] - z0;
  out[(size_t)bi * Ln + j] = sqrtf(dx * dx + dy * dy + dz * dz + 1e-12f);
}

// ---------------------------------------------------------------------------
extern "C" void kernel_launch(void* const* d_in, const int* in_sizes, int n_in,
                              void* d_out, int out_size, void* d_ws, size_t ws_size,
                              hipStream_t stream)
{
  const float* z     = (const float*)d_in[0];
  const float* x     = (const float*)d_in[1];
  const float* pos   = (const float*)d_in[2];
  const float* aa    = (const float*)d_in[3];
  const float* ex_w1 = (const float*)d_in[4];
  const float* ex_b1 = (const float*)d_in[5];
  const float* ex_w2 = (const float*)d_in[6];
  const float* ex_b2 = (const float*)d_in[7];
  const float* Wq    = (const float*)d_in[8];
  const float* Wk    = (const float*)d_in[9];
  const float* Wv    = (const float*)d_in[10];
  const float* Wo    = (const float*)d_in[11];
  const float* bo    = (const float*)d_in[12];
  const float* W2d   = (const float*)d_in[13];
  const float* b2d   = (const float*)d_in[14];
  const float* W1    = (const float*)d_in[15];
  const float* b1    = (const float*)d_in[16];
  const float* W2    = (const float*)d_in[17];
  const float* b2    = (const float*)d_in[18];
  const float* g1    = (const float*)d_in[19];
  const float* be1   = (const float*)d_in[20];
  const float* g2    = (const float*)d_in[21];
  const float* be2   = (const float*)d_in[22];
  const float* m3w1  = (const float*)d_in[23];
  const float* m3b1  = (const float*)d_in[24];
  const float* m3w2  = (const float*)d_in[25];
  const float* m3b2  = (const float*)d_in[26];

  float* ws     = (float*)d_ws;
  float* h      = ws;                          // 4096*256
  float* t0     = h + (size_t)ROWS * E;        // 4096*256 (embed hidden / tmp)
  float* r      = t0 + (size_t)ROWS * E;       // 4096*3
  float* bias49 = r + (size_t)ROWS * 3;        // 8*16*49
  unsigned short* us = (unsigned short*)(bias49 + NL * NH * 49);
  unsigned short* hb   = us;                              // 4096*256
  unsigned short* umb  = hb  + (size_t)ROWS * E;          // 4096*288
  unsigned short* qkvb = umb + (size_t)ROWS * (E + E1D);  // 4096*1536
  unsigned short* ob   = qkvb + (size_t)ROWS * 3 * DM;    // 4096*512
  unsigned short* t1b  = ob  + (size_t)ROWS * DM;         // 4096*1024
  unsigned short* qkvT = t1b + (size_t)ROWS * FF;         // 8*1536*256
  unsigned short* WoT  = qkvT + (size_t)NL * 3 * DM * E;  // 8*256*512
  unsigned short* W1T  = WoT  + (size_t)NL * E * DM;      // 8*1024*288
  unsigned short* W2T  = W1T  + (size_t)NL * FF * (E+E1D);// 8*256*1024
  float* t1f = (float*)t1b;   // head scratch aliases t1b

  // ---- weight transpose+convert (4 launches) ----
  transpose_qkv<<<dim3(DM/32, E/32, 3*NL), 256, 0, stream>>>(Wq, Wk, Wv, qkvT);
  transpose_bf16<<<dim3(E/32, DM/32, NL), 256, 0, stream>>>(
      Wo, WoT, DM, E, (size_t)DM * E, (size_t)DM * E);
  transpose_bf16<<<dim3(FF/32, (E+E1D)/32, NL), 256, 0, stream>>>(
      W1, W1T, E + E1D, FF, (size_t)(E+E1D) * FF, (size_t)(E+E1D) * FF);
  transpose_bf16<<<dim3(E/32, FF/32, NL), 256, 0, stream>>>(
      W2, W2T, FF, E, (size_t)FF * E, (size_t)FF * E);

  embed1_kernel<<<ROWS, 256, 0, stream>>>(z, x, aa, ex_w1, ex_b1, t0, umb);
  gemm64f<false,true,true><<<dim3(E/64, ROWS/64), 256, 0, stream>>>(
      t0, ex_w2, ex_b2, h, hb, E, E);
  bias_kernel<<<NL, 256, 0, stream>>>(pos, W2d, b2d, bias49);

  for (int i = 0; i < NL; ++i) {
    // fused QKV: N=1536, 64x128 tiles, BK=128 -> 768 blocks (3/CU), 2 K-steps
    gemm_mfma<64,128,128,false,false,true,true><<<dim3(12, 64), 256, 0, stream>>>(
        hb, qkvT + (size_t)i * 3 * DM * E, nullptr, nullptr, qkvb, 3 * DM, E);
    // attention: 1D grid 1024 with XCD-locality remap (see kernel comment)
    attn_kernel<<<dim3(1024), 256, 0, stream>>>(
        qkvb, bias49 + (size_t)i * NH * 49, ob);
    // fused Wo + bias + resid + LN1 -> h, umb  (256 blocks, 4 K-steps)
    gemm_ln<<<ROWS/16, 256, 0, stream>>>(
        ob, WoT + (size_t)i * DM * E, bo + (size_t)i * E, h,
        g1 + (size_t)i * E, be1 + (size_t)i * E, umb, E + E1D, DM);
    // FF1 + bias + relu -> bf16 t1b  (64x64 tiles, BK=32 -> 1024 blocks, 4/CU)
    gemm_mfma<64,64,32,true,true,true,false><<<dim3(FF/64, ROWS/64), 256, 0, stream>>>(
        umb, W1T + (size_t)i * FF * (E+E1D), b1 + (size_t)i * FF, nullptr, t1b, FF, E + E1D);
    // fused FF2 + bias + resid + LN2 -> h, hb  (256 blocks, 8 K-steps)
    gemm_ln<<<ROWS/16, 256, 0, stream>>>(
        t1b, W2T + (size_t)i * E * FF, b2 + (size_t)i * E, h,
        g2 + (size_t)i * E, be2 + (size_t)i * E, hb, E, FF);
  }

  // fp32 head
  gemm64f<true,true,false><<<dim3(E/64, ROWS/64), 256, 0, stream>>>(
      h, m3w1, m3b1, t1f, nullptr, E, E);
  final_r_kernel<<<ROWS, 256, 0, stream>>>(t1f, m3w2, m3b2, r);
  dist_kernel<<<ROWS, 512, 0, stream>>>(r, (float*)d_out);
}

// Round 9
// 773.216 us; speedup vs baseline: 1.1150x; 1.0405x over previous
//
#include <hip/hip_runtime.h>
#include <math.h>

constexpr int Bn = 8, NZ = 16, Ln = 512;
constexpr int E = 256, DM = 512, NH = 16, HD = 32;
constexpr int FF = 1024, NL = 8, E1D = 32, PDIM = 64, PMAX = 24;
constexpr int ROWS = Bn * Ln;                       // 4096
constexpr float QSCALE = 0.04419417382415922f;      // 1/sqrt(512)

typedef __attribute__((ext_vector_type(8))) short bf16x8;
typedef __attribute__((ext_vector_type(4))) float floatx4;

__device__ inline unsigned short f2b(float f) {
  union { float f; unsigned u; } v; v.f = f;
  unsigned r = (v.u + 0x7FFF + ((v.u >> 16) & 1)) >> 16;
  return (unsigned short)r;
}
__device__ inline float b2f(unsigned short u) {
  union { unsigned u; float f; } v; v.u = ((unsigned)u) << 16; return v.f;
}

// async global->LDS DMA, 16B per lane; LDS dest is wave-uniform base + lane*16
// (m104 semantics). Compiler drains vmcnt(0) at __syncthreads -> data visible.
__device__ inline void gll16(const void* g, void* l) {
  __builtin_amdgcn_global_load_lds(
      (const __attribute__((address_space(1))) void*)g,
      (__attribute__((address_space(3))) void*)l, 16, 0, 0);
}

// fmax with a DPP-permuted copy (register-only cross-lane; replaces
// ds_bpermute-based __shfl_xor for MAX reductions). fmax over the same
// value set is order-invariant bit-exact -> numerics unchanged.
template<int CTRL>
__device__ inline float fmax_dpp(float x) {
  int y = __builtin_amdgcn_update_dpp(0, __float_as_int(x), CTRL, 0xf, 0xf, true);
  return fmaxf(x, __int_as_float(y));
}

// ---------------------------------------------------------------------------
// batched Wq/Wk/Wv fp32 [l][E][DM] -> bf16 qkvT [l][3*DM][E]
// ---------------------------------------------------------------------------
__global__ __launch_bounds__(256) void transpose_qkv(
    const float* __restrict__ Wq, const float* __restrict__ Wk,
    const float* __restrict__ Wv, unsigned short* __restrict__ qkvT)
{
  __shared__ float t[32][33];
  int zb = blockIdx.z;
  int which = zb / NL, l = zb % NL;
  const float* s = (which == 0 ? Wq : which == 1 ? Wk : Wv) + (size_t)l * E * DM;
  unsigned short* d = qkvT + (size_t)l * 3 * DM * E + (size_t)which * DM * E;
  int c0 = blockIdx.x * 32, r0 = blockIdx.y * 32;
  int tx = threadIdx.x & 31, ty = threadIdx.x >> 5;
  #pragma unroll
  for (int i = 0; i < 4; ++i)
    t[ty + i * 8][tx] = s[(size_t)(r0 + ty + i * 8) * DM + c0 + tx];
  __syncthreads();
  #pragma unroll
  for (int i = 0; i < 4; ++i)
    d[(size_t)(c0 + ty + i * 8) * E + r0 + tx] = f2b(t[tx][ty + i * 8]);
}

// ---------------------------------------------------------------------------
// generic fp32 [l][R][C] -> bf16 [l][C][R]
// ---------------------------------------------------------------------------
__global__ __launch_bounds__(256) void transpose_bf16(
    const float* __restrict__ src, unsigned short* __restrict__ dst,
    int R, int C, size_t sls, size_t dls)
{
  __shared__ float t[32][33];
  int l = blockIdx.z;
  int c0 = blockIdx.x * 32, r0 = blockIdx.y * 32;
  int tx = threadIdx.x & 31, ty = threadIdx.x >> 5;
  const float* s = src + (size_t)l * sls;
  unsigned short* d = dst + (size_t)l * dls;
  #pragma unroll
  for (int i = 0; i < 4; ++i)
    t[ty + i * 8][tx] = s[(size_t)(r0 + ty + i * 8) * C + c0 + tx];
  __syncthreads();
  #pragma unroll
  for (int i = 0; i < 4; ++i)
    d[(size_t)(c0 + ty + i * 8) * R + r0 + tx] = f2b(t[tx][ty + i * 8]);
}

// ---------------------------------------------------------------------------
// embed stage 1: t0 = relu(z^T @ ex_w1 + b1) fp32; e_aa gather into umb
// ---------------------------------------------------------------------------
__global__ __launch_bounds__(256) void embed1_kernel(
    const float* __restrict__ z, const float* __restrict__ x,
    const float* __restrict__ aa,
    const float* __restrict__ w1, const float* __restrict__ b1,
    float* __restrict__ t0, unsigned short* __restrict__ umb)
{
  int row = blockIdx.x;
  int b = row >> 9, l = row & (Ln - 1);
  int t = threadIdx.x;
  __shared__ float zs[NZ];
  __shared__ int am_s;
  if (t < NZ) zs[t] = z[((size_t)b * NZ + t) * Ln + l];
  if (t == 0) {
    const float* xp = x + (size_t)b * 20 * Ln + l;
    int am = 0; float bv = xp[0];
    for (int c = 1; c < 20; ++c) { float vv = xp[(size_t)c * Ln]; if (vv > bv) { bv = vv; am = c; } }
    am_s = am;
  }
  __syncthreads();
  float a1 = b1[t];
  #pragma unroll
  for (int nz = 0; nz < NZ; ++nz) a1 += zs[nz] * w1[nz * E + t];
  t0[(size_t)row * E + t] = fmaxf(a1, 0.f);
  if (t < E1D) umb[(size_t)row * (E + E1D) + E + t] = f2b(aa[am_s * E1D + t]);
}

// ---------------------------------------------------------------------------
// pairwise-bias collapse: 49 bins per (layer, head)
// ---------------------------------------------------------------------------
__global__ __launch_bounds__(256) void bias_kernel(
    const float* __restrict__ pos, const float* __restrict__ W2d,
    const float* __restrict__ b2d, float* __restrict__ bias49)
{
  int layer = blockIdx.x;
  for (int idx = threadIdx.x; idx < NH * 49; idx += 256) {
    int hh = idx / 49, bin = idx % 49;
    float acc = b2d[layer * NH + hh];
    for (int p = 0; p < PDIM; ++p)
      acc += pos[bin * PDIM + p] * W2d[((size_t)layer * PDIM + p) * NH + hh];
    bias49[(size_t)layer * NH * 49 + hh * 49 + bin] = acc;
  }
}

// ---------------------------------------------------------------------------
// bf16 MFMA GEMM. BK in {32, 128}. (R17-proven, unchanged)
// ---------------------------------------------------------------------------
template<int BM, int BN, int BK, bool BIAS, bool RELU, bool OUTBF16, bool QKV>
__global__ __launch_bounds__(256) void gemm_mfma(
    const unsigned short* __restrict__ A, const unsigned short* __restrict__ Bt,
    const float* __restrict__ bias,
    float* __restrict__ Cf, unsigned short* __restrict__ Cb, int N, int K)
{
  constexpr int MT = BM / 32, NT = BN / 32;
  __shared__ __align__(16) unsigned short As[BM][BK];
  __shared__ __align__(16) unsigned short Bs[BN][BK];
  const int tid = threadIdx.x;
  const int wave = tid >> 6, ln = tid & 63;
  const int quad = ln >> 4, l16 = ln & 15;
  const int wm = wave >> 1, wn = wave & 1;
  const int m0 = blockIdx.y * BM, n0 = blockIdx.x * BN;

  floatx4 acc[MT][NT] = {};

  if constexpr (BK == 32) {
    // 16 rows per wave-issue, 4x16B chunks per 64B row
    const int lrow = ln >> 2, chunk = ln & 3;
    const int schunk = chunk ^ ((lrow >> 1) & 3);
    const unsigned short* aSrc = A + (size_t)(m0 + wave * 16 + lrow) * K + schunk * 8;
    const unsigned short* bSrc = Bt + (size_t)(n0 + wave * 16 + lrow) * K + schunk * 8;
    const int rkey = (l16 >> 1) & 3;

    for (int kb = 0; kb < K; kb += 32) {
      __syncthreads();
      #pragma unroll
      for (int it = 0; it < BM / 64; ++it)
        gll16(aSrc + (size_t)it * 64 * K + kb, &As[it * 64 + wave * 16][0]);
      #pragma unroll
      for (int it = 0; it < BN / 64; ++it)
        gll16(bSrc + (size_t)it * 64 * K + kb, &Bs[it * 64 + wave * 16][0]);
      __syncthreads();
      bf16x8 af[MT], bfr[NT];
      #pragma unroll
      for (int i = 0; i < MT; ++i)
        af[i] = *(const bf16x8*)&As[wm * (BM / 2) + i * 16 + l16][(quad ^ rkey) * 8];
      #pragma unroll
      for (int j = 0; j < NT; ++j)
        bfr[j] = *(const bf16x8*)&Bs[wn * (BN / 2) + j * 16 + l16][(quad ^ rkey) * 8];
      #pragma unroll
      for (int i = 0; i < MT; ++i)
        #pragma unroll
        for (int j = 0; j < NT; ++j)
          acc[i][j] = __builtin_amdgcn_mfma_f32_16x16x32_bf16(af[i], bfr[j], acc[i][j], 0, 0, 0);
    }
  } else {
    // BK=128: 4 rows per wave-issue, 16x16B chunks per 256B row.
    const int lrow = ln >> 4, chunk = ln & 15;
    const int key = wave * 4 + lrow;              // < 16
    const int schunk = chunk ^ key;
    const unsigned short* aSrc = A + (size_t)(m0 + key) * K + schunk * 8;
    const unsigned short* bSrc = Bt + (size_t)(n0 + key) * K + schunk * 8;

    for (int kb = 0; kb < K; kb += 128) {
      __syncthreads();
      #pragma unroll
      for (int it = 0; it < BM / 16; ++it)
        gll16(aSrc + (size_t)(it * 16) * K + kb, &As[it * 16 + wave * 4][0]);
      #pragma unroll
      for (int it = 0; it < BN / 16; ++it)
        gll16(bSrc + (size_t)(it * 16) * K + kb, &Bs[it * 16 + wave * 4][0]);
      __syncthreads();
      #pragma unroll
      for (int kc = 0; kc < 4; ++kc) {
        bf16x8 af[MT], bfr[NT];
        #pragma unroll
        for (int i = 0; i < MT; ++i)
          af[i] = *(const bf16x8*)&As[wm * (BM / 2) + i * 16 + l16][(((kc * 4 + quad) ^ l16) * 8)];
        #pragma unroll
        for (int j = 0; j < NT; ++j)
          bfr[j] = *(const bf16x8*)&Bs[wn * (BN / 2) + j * 16 + l16][(((kc * 4 + quad) ^ l16) * 8)];
        #pragma unroll
        for (int i = 0; i < MT; ++i)
          #pragma unroll
          for (int j = 0; j < NT; ++j)
            acc[i][j] = __builtin_amdgcn_mfma_f32_16x16x32_bf16(af[i], bfr[j], acc[i][j], 0, 0, 0);
      }
    }
  }

  #pragma unroll
  for (int i = 0; i < MT; ++i)
    #pragma unroll
    for (int j = 0; j < NT; ++j) {
      int col = n0 + wn * (BN / 2) + j * 16 + l16;
      float bv = BIAS ? bias[col] : 0.f;
      float sc = QKV ? (col < 512 ? QSCALE : 1.f) : 1.f;
      #pragma unroll
      for (int r = 0; r < 4; ++r) {
        int rowg = m0 + wm * (BM / 2) + i * 16 + quad * 4 + r;
        float v = acc[i][j][r] * sc + bv;
        if (RELU) v = fmaxf(v, 0.f);
        if (OUTBF16) Cb[(size_t)rowg * N + col] = f2b(v);
        else Cf[(size_t)rowg * N + col] = v;
      }
    }
}

// ---------------------------------------------------------------------------
// Fused GEMM(+bias+resid) + LayerNorm, N = 256. (R17-proven, unchanged)
// ---------------------------------------------------------------------------
__global__ __launch_bounds__(256) void gemm_ln(
    const unsigned short* __restrict__ A, const unsigned short* __restrict__ Bt,
    const float* __restrict__ bias, float* __restrict__ h,
    const float* __restrict__ g, const float* __restrict__ be,
    unsigned short* __restrict__ outb, int bstride, int K)
{
  __shared__ __align__(16) unsigned short As[16][128];
  __shared__ __align__(16) unsigned short Bs[256][128];
  __shared__ __align__(16) float vtile[16][260];   // +4 pad: scatter 2-way max
  const int tid = threadIdx.x;
  const int w = tid >> 6, ln = tid & 63;
  const int quad = ln >> 4, l16 = ln & 15;
  const int m0 = blockIdx.x * 16;
  const int lrow = ln >> 4, chunk = ln & 15;
  const int key = w * 4 + lrow;                   // row & 15
  const int schunk = chunk ^ key;
  const unsigned short* aSrc = A + (size_t)(m0 + key) * K + schunk * 8;
  const unsigned short* bSrc = Bt + (size_t)key * K + schunk * 8;

  floatx4 acc[4] = {};

  for (int kb = 0; kb < K; kb += 128) {
    __syncthreads();
    gll16(aSrc + kb, &As[w * 4][0]);
    #pragma unroll
    for (int it = 0; it < 16; ++it)
      gll16(bSrc + (size_t)(it * 16) * K + kb, &Bs[it * 16 + w * 4][0]);
    __syncthreads();
    #pragma unroll
    for (int kc = 0; kc < 4; ++kc) {
      bf16x8 af = *(const bf16x8*)&As[l16][(((kc * 4 + quad) ^ l16) * 8)];
      #pragma unroll
      for (int nt = 0; nt < 4; ++nt) {
        bf16x8 bf = *(const bf16x8*)&Bs[w * 64 + nt * 16 + l16][(((kc * 4 + quad) ^ l16) * 8)];
        acc[nt] = __builtin_amdgcn_mfma_f32_16x16x32_bf16(af, bf, acc[nt], 0, 0, 0);
      }
    }
  }

  // v = (acc + bias) + resid — same op order as old gemm_n256 epilogue
  #pragma unroll
  for (int nt = 0; nt < 4; ++nt) {
    int col = w * 64 + nt * 16 + l16;
    float bv = bias[col];
    #pragma unroll
    for (int r = 0; r < 4; ++r) {
      int row = quad * 4 + r;
      vtile[row][col] = acc[nt][r] + bv + h[(size_t)(m0 + row) * E + col];
    }
  }
  __syncthreads();

  // LN phase — bitwise replica of ln_kernel (wave-per-row, float4 lanes)
  const int c0 = ln * 4;
  #pragma unroll
  for (int rr = 0; rr < 4; ++rr) {
    const int lr = w * 4 + rr;
    float4 v = *(const float4*)&vtile[lr][c0];
    float s = v.x + v.y + v.z + v.w;
    float s2 = v.x * v.x + v.y * v.y + v.z * v.z + v.w * v.w;
    #pragma unroll
    for (int off = 1; off < 64; off <<= 1) {
      s += __shfl_xor(s, off, 64);
      s2 += __shfl_xor(s2, off, 64);
    }
    const float mean = s * (1.f / E);
    const float rstd = rsqrtf(s2 * (1.f / E) - mean * mean + 1e-5f);
    const float4 gv = *(const float4*)(g + c0);
    const float4 bv = *(const float4*)(be + c0);
    float4 y;
    y.x = (v.x - mean) * rstd * gv.x + bv.x;
    y.y = (v.y - mean) * rstd * gv.y + bv.y;
    y.z = (v.z - mean) * rstd * gv.z + bv.z;
    y.w = (v.w - mean) * rstd * gv.w + bv.w;
    const size_t row = (size_t)(m0 + lr);
    *(float4*)(h + row * E + c0) = y;
    ushort4 yb;
    yb.x = f2b(y.x); yb.y = f2b(y.y); yb.z = f2b(y.z); yb.w = f2b(y.w);
    *(ushort4*)(outb + row * (size_t)bstride + c0) = yb;
  }
}

// ---------------------------------------------------------------------------
// MFMA flash attention. R21 = R20 (dbuf, one barrier/tile, prefetch after
// barrier, XCD-locality remap) + DPP max-reduce: the mloc tree's 4
// ds_bpermute-based __shfl_xor are replaced with register-only DPP fmax
// (quad_perm xor1/xor2, row_ror:4/8 merging quads) — covers the same
// 16-lane set, and fmax over the same set is order-invariant bit-exact.
// psum tree (addition: order-sensitive) stays on __shfl_xor. Removes 16
// of 32 LDS cross-lane ops per tile and shortens the softmax serial
// chain. Output bitwise identical.
// ---------------------------------------------------------------------------
__global__ __launch_bounds__(256) void attn_kernel(
    const unsigned short* __restrict__ qkv, const float* __restrict__ bias49,
    unsigned short* __restrict__ o)
{
  const int id = blockIdx.x;
  const int bh = ((id >> 6) << 3) | (id & 7);
  const int i0 = ((id >> 3) & 7) * 64;
  const int b = bh >> 4, hh = bh & 15;
  const int tid = threadIdx.x;
  const int wave = tid >> 6, ln = tid & 63;
  const int quad = ln >> 4, l16 = ln & 15;

  __shared__ __align__(16) unsigned short Kt[2][64][40];
  __shared__ __align__(16) unsigned short Vt[2][32][72];
  __shared__ __align__(16) unsigned short Pw[4][2][16][72];
  __shared__ float bsh[49];

  if (tid < 49) bsh[tid] = bias49[hh * 49 + tid];

  const unsigned short* qkvb = qkv + (size_t)b * Ln * 1536;

  const int qrow = i0 + wave * 16 + l16;
  const bf16x8 qf = *(const bf16x8*)(qkvb + (size_t)qrow * 1536 + hh * 32 + quad * 8);

  float m[4], l[4];
  #pragma unroll
  for (int r = 0; r < 4; ++r) { m[r] = -1e30f; l[r] = 0.f; }
  floatx4 acc_o[2] = {};

  const int krow = tid >> 2, kch = (tid & 3) * 8;
  const int vkey = tid & 63, vch = (tid >> 6) * 8;
  const unsigned short* kp = qkvb + (size_t)krow * 1536 + 512 + hh * 32 + kch;
  const unsigned short* vp = qkvb + (size_t)vkey * 1536 + 1024 + hh * 32 + vch;

  float4 kreg = *(const float4*)kp;
  bf16x8 vreg = *(const bf16x8*)vp;

  for (int jt = 0; jt < 8; ++jt) {
    const int j0 = jt * 64;
    const int cur = jt & 1;
    *(float4*)&Kt[cur][krow][kch] = kreg;
    #pragma unroll
    for (int i = 0; i < 8; ++i) Vt[cur][vch + i][vkey] = (unsigned short)vreg[i];
    __syncthreads();
    if (jt < 7) {   // AFTER barrier: latency hides under this tile's compute
      kreg = *(const float4*)(kp + (size_t)(j0 + 64) * 1536);
      vreg = *(const bf16x8*)(vp + (size_t)(j0 + 64) * 1536);
    }

    floatx4 s4[4];
    #pragma unroll
    for (int t = 0; t < 4; ++t) {
      bf16x8 kf = *(const bf16x8*)&Kt[cur][16 * t + l16][quad * 8];
      s4[t] = __builtin_amdgcn_mfma_f32_16x16x32_bf16(qf, kf, (floatx4){0.f, 0.f, 0.f, 0.f}, 0, 0, 0);
    }
    const int relmin = j0 - (i0 + 63), relmax = j0 + 63 - i0;
    if (relmin >= PMAX) {
      float bc = bsh[48];
      #pragma unroll
      for (int t = 0; t < 4; ++t)
        #pragma unroll
        for (int r = 0; r < 4; ++r) s4[t][r] += bc;
    } else if (relmax <= -PMAX) {
      float bc = bsh[0];
      #pragma unroll
      for (int t = 0; t < 4; ++t)
        #pragma unroll
        for (int r = 0; r < 4; ++r) s4[t][r] += bc;
    } else {
      const int base_rel = (j0 + l16) - (i0 + wave * 16 + quad * 4);
      #pragma unroll
      for (int t = 0; t < 4; ++t)
        #pragma unroll
        for (int r = 0; r < 4; ++r) {
          int rel = base_rel + 16 * t - r;
          rel = rel < -PMAX ? -PMAX : (rel > PMAX ? PMAX : rel);
          s4[t][r] += bsh[rel + PMAX];
        }
    }

    float mloc[4], alpha[4], psum[4];
    #pragma unroll
    for (int r = 0; r < 4; ++r) {
      mloc[r] = fmaxf(fmaxf(s4[0][r], s4[1][r]), fmaxf(s4[2][r], s4[3][r]));
      // 16-lane max reduce via DPP (register-only; same value set as the
      // old xor-tree -> bit-identical result, no LDS round-trips):
      mloc[r] = fmax_dpp<0xB1>(mloc[r]);   // quad_perm(1,0,3,2) = xor1
      mloc[r] = fmax_dpp<0x4E>(mloc[r]);   // quad_perm(2,3,0,1) = xor2
      mloc[r] = fmax_dpp<0x124>(mloc[r]);  // row_ror:4  (merge quad pairs)
      mloc[r] = fmax_dpp<0x128>(mloc[r]);  // row_ror:8  (merge all quads)
      float mnew = fmaxf(m[r], mloc[r]);
      alpha[r] = __expf(m[r] - mnew);
      m[r] = mnew;
      psum[r] = 0.f;
    }
    #pragma unroll
    for (int t = 0; t < 4; ++t)
      #pragma unroll
      for (int r = 0; r < 4; ++r) {
        float p = __expf(s4[t][r] - m[r]);
        s4[t][r] = p;
        psum[r] += p;
      }
    #pragma unroll
    for (int r = 0; r < 4; ++r) {
      #pragma unroll
      for (int off = 1; off < 16; off <<= 1)
        psum[r] += __shfl_xor(psum[r], off, 64);
      l[r] = l[r] * alpha[r] + psum[r];
      acc_o[0][r] *= alpha[r];
      acc_o[1][r] *= alpha[r];
    }

    #pragma unroll
    for (int t = 0; t < 4; ++t)
      #pragma unroll
      for (int r = 0; r < 4; ++r) {
        float p = s4[t][r];
        unsigned short hi = f2b(p);
        unsigned short lo = f2b(p - b2f(hi));
        Pw[wave][0][quad * 4 + r][16 * t + l16] = hi;
        Pw[wave][1][quad * 4 + r][16 * t + l16] = lo;
      }

    #pragma unroll
    for (int kh = 0; kh < 2; ++kh) {
      bf16x8 phi = *(const bf16x8*)&Pw[wave][0][l16][kh * 32 + quad * 8];
      bf16x8 plo = *(const bf16x8*)&Pw[wave][1][l16][kh * 32 + quad * 8];
      #pragma unroll
      for (int nt = 0; nt < 2; ++nt) {
        bf16x8 vf = *(const bf16x8*)&Vt[cur][nt * 16 + l16][kh * 32 + quad * 8];
        acc_o[nt] = __builtin_amdgcn_mfma_f32_16x16x32_bf16(phi, vf, acc_o[nt], 0, 0, 0);
        acc_o[nt] = __builtin_amdgcn_mfma_f32_16x16x32_bf16(plo, vf, acc_o[nt], 0, 0, 0);
      }
    }
  }

  #pragma unroll
  for (int r = 0; r < 4; ++r) {
    float inv = 1.f / l[r];
    size_t rowg = (size_t)b * Ln + i0 + wave * 16 + quad * 4 + r;
    #pragma unroll
    for (int nt = 0; nt < 2; ++nt)
      o[rowg * 512 + hh * 32 + nt * 16 + l16] = f2b(acc_o[nt][r] * inv);
  }
}

// ---------------------------------------------------------------------------
// fp32 tiled GEMM: C = act(A@B + bias), optional bf16 mirror (embed2 / head)
// ---------------------------------------------------------------------------
template<bool RELU, bool BIAS, bool MIRROR>
__global__ __launch_bounds__(256) void gemm64f(
    const float* __restrict__ A, const float* __restrict__ B,
    const float* __restrict__ bias, float* __restrict__ C,
    unsigned short* __restrict__ mir, int N, int K)
{
  __shared__ __align__(16) float As[16][64];
  __shared__ __align__(16) float Bss[16][68];
  const int tid = threadIdx.x;
  const int tx = tid & 15, ty = tid >> 4;
  const int m0 = blockIdx.y * 64, n0 = blockIdx.x * 64;
  const int arow = tid >> 2, acol = (tid & 3) * 4;
  const int brow = tid >> 6, bcol = tid & 63;
  float acc[4][4] = {};
  for (int kb = 0; kb < K; kb += 16) {
    __syncthreads();
    float4 av = *(const float4*)(A + (size_t)(m0 + arow) * K + kb + acol);
    As[acol + 0][arow] = av.x; As[acol + 1][arow] = av.y;
    As[acol + 2][arow] = av.z; As[acol + 3][arow] = av.w;
    #pragma unroll
    for (int kk = 0; kk < 4; ++kk)
      Bss[brow + kk * 4][bcol] = B[(size_t)(kb + brow + kk * 4) * N + n0 + bcol];
    __syncthreads();
    #pragma unroll
    for (int k = 0; k < 16; ++k) {
      float4 a = *(const float4*)&As[k][4 * ty];
      float4 b = *(const float4*)&Bss[k][4 * tx];
      float av4[4] = {a.x, a.y, a.z, a.w};
      float bv4[4] = {b.x, b.y, b.z, b.w};
      #pragma unroll
      for (int ii = 0; ii < 4; ++ii)
        #pragma unroll
        for (int jj = 0; jj < 4; ++jj)
          acc[ii][jj] += av4[ii] * bv4[jj];
    }
  }
  #pragma unroll
  for (int ii = 0; ii < 4; ++ii) {
    size_t row = (size_t)m0 + 4 * ty + ii;
    int col = n0 + 4 * tx;
    float4 vv;
    vv.x = acc[ii][0]; vv.y = acc[ii][1]; vv.z = acc[ii][2]; vv.w = acc[ii][3];
    if (BIAS) {
      float4 bb = *(const float4*)(bias + col);
      vv.x += bb.x; vv.y += bb.y; vv.z += bb.z; vv.w += bb.w;
    }
    if (RELU) {
      vv.x = fmaxf(vv.x, 0.f); vv.y = fmaxf(vv.y, 0.f);
      vv.z = fmaxf(vv.z, 0.f); vv.w = fmaxf(vv.w, 0.f);
    }
    *(float4*)(C + row * N + col) = vv;
    if (MIRROR) {
      ushort4 mv;
      mv.x = f2b(vv.x); mv.y = f2b(vv.y); mv.z = f2b(vv.z); mv.w = f2b(vv.w);
      *(ushort4*)(mir + row * N + col) = mv;
    }
  }
}

__global__ __launch_bounds__(256) void final_r_kernel(
    const float* __restrict__ t1, const float* __restrict__ w2,
    const float* __restrict__ b2, float* __restrict__ r)
{
  int row = blockIdx.x, t = threadIdx.x;
  float xv = t1[(size_t)row * E + t];
  float p0 = xv * w2[t * 3 + 0];
  float p1 = xv * w2[t * 3 + 1];
  float p2 = xv * w2[t * 3 + 2];
  #pragma unroll
  for (int off = 32; off > 0; off >>= 1) {
    p0 += __shfl_down(p0, off, 64);
    p1 += __shfl_down(p1, off, 64);
    p2 += __shfl_down(p2, off, 64);
  }
  __shared__ float red[4][3];
  if ((t & 63) == 0) { int w = t >> 6; red[w][0] = p0; red[w][1] = p1; red[w][2] = p2; }
  __syncthreads();
  if (t < 3)
    r[(size_t)row * 3 + t] = red[0][t] + red[1][t] + red[2][t] + red[3][t] + b2[t];
}

__global__ __launch_bounds__(512) void dist_kernel(
    const float* __restrict__ r, float* __restrict__ out)
{
  int bi = blockIdx.x;
  int j = threadIdx.x;
  int b = bi >> 9;
  float x0 = r[(size_t)bi * 3 + 0];
  float y0 = r[(size_t)bi * 3 + 1];
  float z0 = r[(size_t)bi * 3 + 2];
  const float* rj = r + ((size_t)b * Ln + j) * 3;
  float dx = rj[0] - x0, dy = rj[1] - y0, dz = rj[2] - z0;
  out[(size_t)bi * Ln + j] = sqrtf(dx * dx + dy * dy + dz * dz + 1e-12f);
}

// ---------------------------------------------------------------------------
extern "C" void kernel_launch(void* const* d_in, const int* in_sizes, int n_in,
                              void* d_out, int out_size, void* d_ws, size_t ws_size,
                              hipStream_t stream)
{
  const float* z     = (const float*)d_in[0];
  const float* x     = (const float*)d_in[1];
  const float* pos   = (const float*)d_in[2];
  const float* aa    = (const float*)d_in[3];
  const float* ex_w1 = (const float*)d_in[4];
  const float* ex_b1 = (const float*)d_in[5];
  const float* ex_w2 = (const float*)d_in[6];
  const float* ex_b2 = (const float*)d_in[7];
  const float* Wq    = (const float*)d_in[8];
  const float* Wk    = (const float*)d_in[9];
  const float* Wv    = (const float*)d_in[10];
  const float* Wo    = (const float*)d_in[11];
  const float* bo    = (const float*)d_in[12];
  const float* W2d   = (const float*)d_in[13];
  const float* b2d   = (const float*)d_in[14];
  const float* W1    = (const float*)d_in[15];
  const float* b1    = (const float*)d_in[16];
  const float* W2    = (const float*)d_in[17];
  const float* b2    = (const float*)d_in[18];
  const float* g1    = (const float*)d_in[19];
  const float* be1   = (const float*)d_in[20];
  const float* g2    = (const float*)d_in[21];
  const float* be2   = (const float*)d_in[22];
  const float* m3w1  = (const float*)d_in[23];
  const float* m3b1  = (const float*)d_in[24];
  const float* m3w2  = (const float*)d_in[25];
  const float* m3b2  = (const float*)d_in[26];

  float* ws     = (float*)d_ws;
  float* h      = ws;                          // 4096*256
  float* t0     = h + (size_t)ROWS * E;        // 4096*256 (embed hidden / tmp)
  float* r      = t0 + (size_t)ROWS * E;       // 4096*3
  float* bias49 = r + (size_t)ROWS * 3;        // 8*16*49
  unsigned short* us = (unsigned short*)(bias49 + NL * NH * 49);
  unsigned short* hb   = us;                              // 4096*256
  unsigned short* umb  = hb  + (size_t)ROWS * E;          // 4096*288
  unsigned short* qkvb = umb + (size_t)ROWS * (E + E1D);  // 4096*1536
  unsigned short* ob   = qkvb + (size_t)ROWS * 3 * DM;    // 4096*512
  unsigned short* t1b  = ob  + (size_t)ROWS * DM;         // 4096*1024
  unsigned short* qkvT = t1b + (size_t)ROWS * FF;         // 8*1536*256
  unsigned short* WoT  = qkvT + (size_t)NL * 3 * DM * E;  // 8*256*512
  unsigned short* W1T  = WoT  + (size_t)NL * E * DM;      // 8*1024*288
  unsigned short* W2T  = W1T  + (size_t)NL * FF * (E+E1D);// 8*256*1024
  float* t1f = (float*)t1b;   // head scratch aliases t1b

  // ---- weight transpose+convert (4 launches) ----
  transpose_qkv<<<dim3(DM/32, E/32, 3*NL), 256, 0, stream>>>(Wq, Wk, Wv, qkvT);
  transpose_bf16<<<dim3(E/32, DM/32, NL), 256, 0, stream>>>(
      Wo, WoT, DM, E, (size_t)DM * E, (size_t)DM * E);
  transpose_bf16<<<dim3(FF/32, (E+E1D)/32, NL), 256, 0, stream>>>(
      W1, W1T, E + E1D, FF, (size_t)(E+E1D) * FF, (size_t)(E+E1D) * FF);
  transpose_bf16<<<dim3(E/32, FF/32, NL), 256, 0, stream>>>(
      W2, W2T, FF, E, (size_t)FF * E, (size_t)FF * E);

  embed1_kernel<<<ROWS, 256, 0, stream>>>(z, x, aa, ex_w1, ex_b1, t0, umb);
  gemm64f<false,true,true><<<dim3(E/64, ROWS/64), 256, 0, stream>>>(
      t0, ex_w2, ex_b2, h, hb, E, E);
  bias_kernel<<<NL, 256, 0, stream>>>(pos, W2d, b2d, bias49);

  for (int i = 0; i < NL; ++i) {
    // fused QKV: N=1536, 64x128 tiles, BK=128 -> 768 blocks (3/CU), 2 K-steps
    gemm_mfma<64,128,128,false,false,true,true><<<dim3(12, 64), 256, 0, stream>>>(
        hb, qkvT + (size_t)i * 3 * DM * E, nullptr, nullptr, qkvb, 3 * DM, E);
    // attention: 1D grid 1024 with XCD-locality remap (see kernel comment)
    attn_kernel<<<dim3(1024), 256, 0, stream>>>(
        qkvb, bias49 + (size_t)i * NH * 49, ob);
    // fused Wo + bias + resid + LN1 -> h, umb  (256 blocks, 4 K-steps)
    gemm_ln<<<ROWS/16, 256, 0, stream>>>(
        ob, WoT + (size_t)i * DM * E, bo + (size_t)i * E, h,
        g1 + (size_t)i * E, be1 + (size_t)i * E, umb, E + E1D, DM);
    // FF1 + bias + relu -> bf16 t1b  (64x64 tiles, BK=32 -> 1024 blocks, 4/CU)
    gemm_mfma<64,64,32,true,true,true,false><<<dim3(FF/64, ROWS/64), 256, 0, stream>>>(
        umb, W1T + (size_t)i * FF * (E+E1D), b1 + (size_t)i * FF, nullptr, t1b, FF, E + E1D);
    // fused FF2 + bias + resid + LN2 -> h, hb  (256 blocks, 8 K-steps)
    gemm_ln<<<ROWS/16, 256, 0, stream>>>(
        t1b, W2T + (size_t)i * E * FF, b2 + (size_t)i * E, h,
        g2 + (size_t)i * E, be2 + (size_t)i * E, hb, E, FF);
  }

  // fp32 head
  gemm64f<true,true,false><<<dim3(E/64, ROWS/64), 256, 0, stream>>>(
      h, m3w1, m3b1, t1f, nullptr, E, E);
  final_r_kernel<<<ROWS, 256, 0, stream>>>(t1f, m3w2, m3b2, r);
  dist_kernel<<<ROWS, 512, 0, stream>>>(r, (float*)d_out);
}

// Round 10
// 748.909 us; speedup vs baseline: 1.1512x; 1.0325x over previous
//
#include <hip/hip_runtime.h>
#include <math.h>

constexpr int Bn = 8, NZ = 16, Ln = 512;
constexpr int E = 256, DM = 512, NH = 16, HD = 32;
constexpr int FF = 1024, NL = 8, E1D = 32, PDIM = 64, PMAX = 24;
constexpr int ROWS = Bn * Ln;                       // 4096
constexpr float QSCALE = 0.04419417382415922f;      // 1/sqrt(512)

typedef __attribute__((ext_vector_type(8))) short bf16x8;
typedef __attribute__((ext_vector_type(4))) float floatx4;

__device__ inline unsigned short f2b(float f) {
  union { float f; unsigned u; } v; v.f = f;
  unsigned r = (v.u + 0x7FFF + ((v.u >> 16) & 1)) >> 16;
  return (unsigned short)r;
}
__device__ inline float b2f(unsigned short u) {
  union { unsigned u; float f; } v; v.u = ((unsigned)u) << 16; return v.f;
}

// async global->LDS DMA, 16B per lane; LDS dest is wave-uniform base + lane*16
// (m104 semantics). Compiler drains vmcnt(0) at __syncthreads -> data visible.
__device__ inline void gll16(const void* g, void* l) {
  __builtin_amdgcn_global_load_lds(
      (const __attribute__((address_space(1))) void*)g,
      (__attribute__((address_space(3))) void*)l, 16, 0, 0);
}

// fmax with a DPP-permuted copy (register-only cross-lane). fmax over the
// same value set is order-invariant bit-exact -> numerics unchanged.
template<int CTRL>
__device__ inline float fmax_dpp(float x) {
  int y = __builtin_amdgcn_update_dpp(0, __float_as_int(x), CTRL, 0xf, 0xf, true);
  return fmaxf(x, __int_as_float(y));
}

// fadd with a DPP quad_perm copy. For xor1 (0xB1) / xor2 (0x4E) the partner
// lane is IDENTICAL to __shfl_xor's, and fp add is commutative bitwise ->
// bit-identical to the shfl_xor butterfly level it replaces, minus the LDS op.
template<int CTRL>
__device__ inline float fadd_dpp(float x) {
  int y = __builtin_amdgcn_update_dpp(0, __float_as_int(x), CTRL, 0xf, 0xf, true);
  return x + __int_as_float(y);
}

// ---------------------------------------------------------------------------
// batched Wq/Wk/Wv fp32 [l][E][DM] -> bf16 qkvT [l][3*DM][E]
// ---------------------------------------------------------------------------
__global__ __launch_bounds__(256) void transpose_qkv(
    const float* __restrict__ Wq, const float* __restrict__ Wk,
    const float* __restrict__ Wv, unsigned short* __restrict__ qkvT)
{
  __shared__ float t[32][33];
  int zb = blockIdx.z;
  int which = zb / NL, l = zb % NL;
  const float* s = (which == 0 ? Wq : which == 1 ? Wk : Wv) + (size_t)l * E * DM;
  unsigned short* d = qkvT + (size_t)l * 3 * DM * E + (size_t)which * DM * E;
  int c0 = blockIdx.x * 32, r0 = blockIdx.y * 32;
  int tx = threadIdx.x & 31, ty = threadIdx.x >> 5;
  #pragma unroll
  for (int i = 0; i < 4; ++i)
    t[ty + i * 8][tx] = s[(size_t)(r0 + ty + i * 8) * DM + c0 + tx];
  __syncthreads();
  #pragma unroll
  for (int i = 0; i < 4; ++i)
    d[(size_t)(c0 + ty + i * 8) * E + r0 + tx] = f2b(t[tx][ty + i * 8]);
}

// ---------------------------------------------------------------------------
// generic fp32 [l][R][C] -> bf16 [l][C][R]
// ---------------------------------------------------------------------------
__global__ __launch_bounds__(256) void transpose_bf16(
    const float* __restrict__ src, unsigned short* __restrict__ dst,
    int R, int C, size_t sls, size_t dls)
{
  __shared__ float t[32][33];
  int l = blockIdx.z;
  int c0 = blockIdx.x * 32, r0 = blockIdx.y * 32;
  int tx = threadIdx.x & 31, ty = threadIdx.x >> 5;
  const float* s = src + (size_t)l * sls;
  unsigned short* d = dst + (size_t)l * dls;
  #pragma unroll
  for (int i = 0; i < 4; ++i)
    t[ty + i * 8][tx] = s[(size_t)(r0 + ty + i * 8) * C + c0 + tx];
  __syncthreads();
  #pragma unroll
  for (int i = 0; i < 4; ++i)
    d[(size_t)(c0 + ty + i * 8) * R + r0 + tx] = f2b(t[tx][ty + i * 8]);
}

// ---------------------------------------------------------------------------
// embed stage 1: t0 = relu(z^T @ ex_w1 + b1) fp32; e_aa gather into umb
// ---------------------------------------------------------------------------
__global__ __launch_bounds__(256) void embed1_kernel(
    const float* __restrict__ z, const float* __restrict__ x,
    const float* __restrict__ aa,
    const float* __restrict__ w1, const float* __restrict__ b1,
    float* __restrict__ t0, unsigned short* __restrict__ umb)
{
  int row = blockIdx.x;
  int b = row >> 9, l = row & (Ln - 1);
  int t = threadIdx.x;
  __shared__ float zs[NZ];
  __shared__ int am_s;
  if (t < NZ) zs[t] = z[((size_t)b * NZ + t) * Ln + l];
  if (t == 0) {
    const float* xp = x + (size_t)b * 20 * Ln + l;
    int am = 0; float bv = xp[0];
    for (int c = 1; c < 20; ++c) { float vv = xp[(size_t)c * Ln]; if (vv > bv) { bv = vv; am = c; } }
    am_s = am;
  }
  __syncthreads();
  float a1 = b1[t];
  #pragma unroll
  for (int nz = 0; nz < NZ; ++nz) a1 += zs[nz] * w1[nz * E + t];
  t0[(size_t)row * E + t] = fmaxf(a1, 0.f);
  if (t < E1D) umb[(size_t)row * (E + E1D) + E + t] = f2b(aa[am_s * E1D + t]);
}

// ---------------------------------------------------------------------------
// pairwise-bias collapse: 49 bins per (layer, head)
// ---------------------------------------------------------------------------
__global__ __launch_bounds__(256) void bias_kernel(
    const float* __restrict__ pos, const float* __restrict__ W2d,
    const float* __restrict__ b2d, float* __restrict__ bias49)
{
  int layer = blockIdx.x;
  for (int idx = threadIdx.x; idx < NH * 49; idx += 256) {
    int hh = idx / 49, bin = idx % 49;
    float acc = b2d[layer * NH + hh];
    for (int p = 0; p < PDIM; ++p)
      acc += pos[bin * PDIM + p] * W2d[((size_t)layer * PDIM + p) * NH + hh];
    bias49[(size_t)layer * NH * 49 + hh * 49 + bin] = acc;
  }
}

// ---------------------------------------------------------------------------
// bf16 MFMA GEMM. BK in {32, 128}. (R17-proven, unchanged)
// ---------------------------------------------------------------------------
template<int BM, int BN, int BK, bool BIAS, bool RELU, bool OUTBF16, bool QKV>
__global__ __launch_bounds__(256) void gemm_mfma(
    const unsigned short* __restrict__ A, const unsigned short* __restrict__ Bt,
    const float* __restrict__ bias,
    float* __restrict__ Cf, unsigned short* __restrict__ Cb, int N, int K)
{
  constexpr int MT = BM / 32, NT = BN / 32;
  __shared__ __align__(16) unsigned short As[BM][BK];
  __shared__ __align__(16) unsigned short Bs[BN][BK];
  const int tid = threadIdx.x;
  const int wave = tid >> 6, ln = tid & 63;
  const int quad = ln >> 4, l16 = ln & 15;
  const int wm = wave >> 1, wn = wave & 1;
  const int m0 = blockIdx.y * BM, n0 = blockIdx.x * BN;

  floatx4 acc[MT][NT] = {};

  if constexpr (BK == 32) {
    // 16 rows per wave-issue, 4x16B chunks per 64B row
    const int lrow = ln >> 2, chunk = ln & 3;
    const int schunk = chunk ^ ((lrow >> 1) & 3);
    const unsigned short* aSrc = A + (size_t)(m0 + wave * 16 + lrow) * K + schunk * 8;
    const unsigned short* bSrc = Bt + (size_t)(n0 + wave * 16 + lrow) * K + schunk * 8;
    const int rkey = (l16 >> 1) & 3;

    for (int kb = 0; kb < K; kb += 32) {
      __syncthreads();
      #pragma unroll
      for (int it = 0; it < BM / 64; ++it)
        gll16(aSrc + (size_t)it * 64 * K + kb, &As[it * 64 + wave * 16][0]);
      #pragma unroll
      for (int it = 0; it < BN / 64; ++it)
        gll16(bSrc + (size_t)it * 64 * K + kb, &Bs[it * 64 + wave * 16][0]);
      __syncthreads();
      bf16x8 af[MT], bfr[NT];
      #pragma unroll
      for (int i = 0; i < MT; ++i)
        af[i] = *(const bf16x8*)&As[wm * (BM / 2) + i * 16 + l16][(quad ^ rkey) * 8];
      #pragma unroll
      for (int j = 0; j < NT; ++j)
        bfr[j] = *(const bf16x8*)&Bs[wn * (BN / 2) + j * 16 + l16][(quad ^ rkey) * 8];
      #pragma unroll
      for (int i = 0; i < MT; ++i)
        #pragma unroll
        for (int j = 0; j < NT; ++j)
          acc[i][j] = __builtin_amdgcn_mfma_f32_16x16x32_bf16(af[i], bfr[j], acc[i][j], 0, 0, 0);
    }
  } else {
    // BK=128: 4 rows per wave-issue, 16x16B chunks per 256B row.
    const int lrow = ln >> 4, chunk = ln & 15;
    const int key = wave * 4 + lrow;              // < 16
    const int schunk = chunk ^ key;
    const unsigned short* aSrc = A + (size_t)(m0 + key) * K + schunk * 8;
    const unsigned short* bSrc = Bt + (size_t)(n0 + key) * K + schunk * 8;

    for (int kb = 0; kb < K; kb += 128) {
      __syncthreads();
      #pragma unroll
      for (int it = 0; it < BM / 16; ++it)
        gll16(aSrc + (size_t)(it * 16) * K + kb, &As[it * 16 + wave * 4][0]);
      #pragma unroll
      for (int it = 0; it < BN / 16; ++it)
        gll16(bSrc + (size_t)(it * 16) * K + kb, &Bs[it * 16 + wave * 4][0]);
      __syncthreads();
      #pragma unroll
      for (int kc = 0; kc < 4; ++kc) {
        bf16x8 af[MT], bfr[NT];
        #pragma unroll
        for (int i = 0; i < MT; ++i)
          af[i] = *(const bf16x8*)&As[wm * (BM / 2) + i * 16 + l16][(((kc * 4 + quad) ^ l16) * 8)];
        #pragma unroll
        for (int j = 0; j < NT; ++j)
          bfr[j] = *(const bf16x8*)&Bs[wn * (BN / 2) + j * 16 + l16][(((kc * 4 + quad) ^ l16) * 8)];
        #pragma unroll
        for (int i = 0; i < MT; ++i)
          #pragma unroll
          for (int j = 0; j < NT; ++j)
            acc[i][j] = __builtin_amdgcn_mfma_f32_16x16x32_bf16(af[i], bfr[j], acc[i][j], 0, 0, 0);
      }
    }
  }

  #pragma unroll
  for (int i = 0; i < MT; ++i)
    #pragma unroll
    for (int j = 0; j < NT; ++j) {
      int col = n0 + wn * (BN / 2) + j * 16 + l16;
      float bv = BIAS ? bias[col] : 0.f;
      float sc = QKV ? (col < 512 ? QSCALE : 1.f) : 1.f;
      #pragma unroll
      for (int r = 0; r < 4; ++r) {
        int rowg = m0 + wm * (BM / 2) + i * 16 + quad * 4 + r;
        float v = acc[i][j][r] * sc + bv;
        if (RELU) v = fmaxf(v, 0.f);
        if (OUTBF16) Cb[(size_t)rowg * N + col] = f2b(v);
        else Cf[(size_t)rowg * N + col] = v;
      }
    }
}

// ---------------------------------------------------------------------------
// Fused GEMM(+bias+resid) + LayerNorm, N = 256.
// R22: single-barrier double-buffered staging pipeline. Per K-step:
//   [barrier: drains loads(t) via compiler vmcnt(0); compute(t-1) done]
//   [issue loads(t+1) -> buf^1]   [compute(t) from buf]
// loads(t) are issued one full compute phase before the barrier that
// drains them, so the drain waits only the residual (grid=256 blocks =
// 1/CU: no cross-block hiding exists, so this intra-block overlap is the
// only way to hide the 68KB/step staging). Hazards: compute(t-1) reads
// buf[(t-1)&1]; loads(t+1) overwrite it only after the barrier that also
// orders compute(t-1). One barrier per step (was 2).
// MFMA order unchanged -> bitwise identical. LDS 152.6KB (<160).
// LN reduce levels 1,2 via DPP quad_perm (bit-identical, see fadd_dpp).
// ---------------------------------------------------------------------------
__global__ __launch_bounds__(256) void gemm_ln(
    const unsigned short* __restrict__ A, const unsigned short* __restrict__ Bt,
    const float* __restrict__ bias, float* __restrict__ h,
    const float* __restrict__ g, const float* __restrict__ be,
    unsigned short* __restrict__ outb, int bstride, int K)
{
  __shared__ __align__(16) unsigned short As[2][16][128];
  __shared__ __align__(16) unsigned short Bs[2][256][128];
  __shared__ __align__(16) float vtile[16][260];   // +4 pad: scatter 2-way max
  const int tid = threadIdx.x;
  const int w = tid >> 6, ln = tid & 63;
  const int quad = ln >> 4, l16 = ln & 15;
  const int m0 = blockIdx.x * 16;
  const int lrow = ln >> 4, chunk = ln & 15;
  const int key = w * 4 + lrow;                   // row & 15
  const int schunk = chunk ^ key;
  const unsigned short* aSrc = A + (size_t)(m0 + key) * K + schunk * 8;
  const unsigned short* bSrc = Bt + (size_t)key * K + schunk * 8;

  floatx4 acc[4] = {};
  const int nk = K >> 7;

  // prologue: issue step-0 loads into buf 0 (drained at first barrier)
  gll16(aSrc, &As[0][w * 4][0]);
  #pragma unroll
  for (int it = 0; it < 16; ++it)
    gll16(bSrc + (size_t)(it * 16) * K, &Bs[0][it * 16 + w * 4][0]);

  for (int t = 0; t < nk; ++t) {
    const int cur = t & 1;
    __syncthreads();   // drains loads(t); compute(t-1) complete
    if (t + 1 < nk) {
      const int kb = (t + 1) << 7;
      gll16(aSrc + kb, &As[cur ^ 1][w * 4][0]);
      #pragma unroll
      for (int it = 0; it < 16; ++it)
        gll16(bSrc + (size_t)(it * 16) * K + kb, &Bs[cur ^ 1][it * 16 + w * 4][0]);
    }
    #pragma unroll
    for (int kc = 0; kc < 4; ++kc) {
      bf16x8 af = *(const bf16x8*)&As[cur][l16][(((kc * 4 + quad) ^ l16) * 8)];
      #pragma unroll
      for (int nt = 0; nt < 4; ++nt) {
        bf16x8 bf = *(const bf16x8*)&Bs[cur][w * 64 + nt * 16 + l16][(((kc * 4 + quad) ^ l16) * 8)];
        acc[nt] = __builtin_amdgcn_mfma_f32_16x16x32_bf16(af, bf, acc[nt], 0, 0, 0);
      }
    }
  }

  // v = (acc + bias) + resid — same op order as old gemm_n256 epilogue
  #pragma unroll
  for (int nt = 0; nt < 4; ++nt) {
    int col = w * 64 + nt * 16 + l16;
    float bv = bias[col];
    #pragma unroll
    for (int r = 0; r < 4; ++r) {
      int row = quad * 4 + r;
      vtile[row][col] = acc[nt][r] + bv + h[(size_t)(m0 + row) * E + col];
    }
  }
  __syncthreads();

  // LN phase — bitwise replica of ln_kernel (wave-per-row, float4 lanes);
  // butterfly levels 1,2 via DPP (same partner lane + add commutativity ->
  // bit-identical), levels 4..32 via shfl_xor.
  const int c0 = ln * 4;
  #pragma unroll
  for (int rr = 0; rr < 4; ++rr) {
    const int lr = w * 4 + rr;
    float4 v = *(const float4*)&vtile[lr][c0];
    float s = v.x + v.y + v.z + v.w;
    float s2 = v.x * v.x + v.y * v.y + v.z * v.z + v.w * v.w;
    s  = fadd_dpp<0xB1>(s);   s  = fadd_dpp<0x4E>(s);
    s2 = fadd_dpp<0xB1>(s2);  s2 = fadd_dpp<0x4E>(s2);
    #pragma unroll
    for (int off = 4; off < 64; off <<= 1) {
      s += __shfl_xor(s, off, 64);
      s2 += __shfl_xor(s2, off, 64);
    }
    const float mean = s * (1.f / E);
    const float rstd = rsqrtf(s2 * (1.f / E) - mean * mean + 1e-5f);
    const float4 gv = *(const float4*)(g + c0);
    const float4 bv = *(const float4*)(be + c0);
    float4 y;
    y.x = (v.x - mean) * rstd * gv.x + bv.x;
    y.y = (v.y - mean) * rstd * gv.y + bv.y;
    y.z = (v.z - mean) * rstd * gv.z + bv.z;
    y.w = (v.w - mean) * rstd * gv.w + bv.w;
    const size_t row = (size_t)(m0 + lr);
    *(float4*)(h + row * E + c0) = y;
    ushort4 yb;
    yb.x = f2b(y.x); yb.y = f2b(y.y); yb.z = f2b(y.z); yb.w = f2b(y.w);
    *(ushort4*)(outb + row * (size_t)bstride + c0) = yb;
  }
}

// ---------------------------------------------------------------------------
// MFMA flash attention. R22 = R21 + psum butterfly levels 1,2 via DPP
// quad_perm adds (bit-identical to shfl_xor levels: same partner lane,
// fp add commutative) — removes 8 more LDS cross-lane ops per tile.
// ---------------------------------------------------------------------------
__global__ __launch_bounds__(256) void attn_kernel(
    const unsigned short* __restrict__ qkv, const float* __restrict__ bias49,
    unsigned short* __restrict__ o)
{
  const int id = blockIdx.x;
  const int bh = ((id >> 6) << 3) | (id & 7);
  const int i0 = ((id >> 3) & 7) * 64;
  const int b = bh >> 4, hh = bh & 15;
  const int tid = threadIdx.x;
  const int wave = tid >> 6, ln = tid & 63;
  const int quad = ln >> 4, l16 = ln & 15;

  __shared__ __align__(16) unsigned short Kt[2][64][40];
  __shared__ __align__(16) unsigned short Vt[2][32][72];
  __shared__ __align__(16) unsigned short Pw[4][2][16][72];
  __shared__ float bsh[49];

  if (tid < 49) bsh[tid] = bias49[hh * 49 + tid];

  const unsigned short* qkvb = qkv + (size_t)b * Ln * 1536;

  const int qrow = i0 + wave * 16 + l16;
  const bf16x8 qf = *(const bf16x8*)(qkvb + (size_t)qrow * 1536 + hh * 32 + quad * 8);

  float m[4], l[4];
  #pragma unroll
  for (int r = 0; r < 4; ++r) { m[r] = -1e30f; l[r] = 0.f; }
  floatx4 acc_o[2] = {};

  const int krow = tid >> 2, kch = (tid & 3) * 8;
  const int vkey = tid & 63, vch = (tid >> 6) * 8;
  const unsigned short* kp = qkvb + (size_t)krow * 1536 + 512 + hh * 32 + kch;
  const unsigned short* vp = qkvb + (size_t)vkey * 1536 + 1024 + hh * 32 + vch;

  float4 kreg = *(const float4*)kp;
  bf16x8 vreg = *(const bf16x8*)vp;

  for (int jt = 0; jt < 8; ++jt) {
    const int j0 = jt * 64;
    const int cur = jt & 1;
    *(float4*)&Kt[cur][krow][kch] = kreg;
    #pragma unroll
    for (int i = 0; i < 8; ++i) Vt[cur][vch + i][vkey] = (unsigned short)vreg[i];
    __syncthreads();
    if (jt < 7) {   // AFTER barrier: latency hides under this tile's compute
      kreg = *(const float4*)(kp + (size_t)(j0 + 64) * 1536);
      vreg = *(const bf16x8*)(vp + (size_t)(j0 + 64) * 1536);
    }

    floatx4 s4[4];
    #pragma unroll
    for (int t = 0; t < 4; ++t) {
      bf16x8 kf = *(const bf16x8*)&Kt[cur][16 * t + l16][quad * 8];
      s4[t] = __builtin_amdgcn_mfma_f32_16x16x32_bf16(qf, kf, (floatx4){0.f, 0.f, 0.f, 0.f}, 0, 0, 0);
    }
    const int relmin = j0 - (i0 + 63), relmax = j0 + 63 - i0;
    if (relmin >= PMAX) {
      float bc = bsh[48];
      #pragma unroll
      for (int t = 0; t < 4; ++t)
        #pragma unroll
        for (int r = 0; r < 4; ++r) s4[t][r] += bc;
    } else if (relmax <= -PMAX) {
      float bc = bsh[0];
      #pragma unroll
      for (int t = 0; t < 4; ++t)
        #pragma unroll
        for (int r = 0; r < 4; ++r) s4[t][r] += bc;
    } else {
      const int base_rel = (j0 + l16) - (i0 + wave * 16 + quad * 4);
      #pragma unroll
      for (int t = 0; t < 4; ++t)
        #pragma unroll
        for (int r = 0; r < 4; ++r) {
          int rel = base_rel + 16 * t - r;
          rel = rel < -PMAX ? -PMAX : (rel > PMAX ? PMAX : rel);
          s4[t][r] += bsh[rel + PMAX];
        }
    }

    float mloc[4], alpha[4], psum[4];
    #pragma unroll
    for (int r = 0; r < 4; ++r) {
      mloc[r] = fmaxf(fmaxf(s4[0][r], s4[1][r]), fmaxf(s4[2][r], s4[3][r]));
      mloc[r] = fmax_dpp<0xB1>(mloc[r]);   // quad_perm(1,0,3,2) = xor1
      mloc[r] = fmax_dpp<0x4E>(mloc[r]);   // quad_perm(2,3,0,1) = xor2
      mloc[r] = fmax_dpp<0x124>(mloc[r]);  // row_ror:4  (merge quad pairs)
      mloc[r] = fmax_dpp<0x128>(mloc[r]);  // row_ror:8  (merge all quads)
      float mnew = fmaxf(m[r], mloc[r]);
      alpha[r] = __expf(m[r] - mnew);
      m[r] = mnew;
      psum[r] = 0.f;
    }
    #pragma unroll
    for (int t = 0; t < 4; ++t)
      #pragma unroll
      for (int r = 0; r < 4; ++r) {
        float p = __expf(s4[t][r] - m[r]);
        s4[t][r] = p;
        psum[r] += p;
      }
    #pragma unroll
    for (int r = 0; r < 4; ++r) {
      psum[r] = fadd_dpp<0xB1>(psum[r]);   // xor1 — bit-identical to shfl_xor
      psum[r] = fadd_dpp<0x4E>(psum[r]);   // xor2
      #pragma unroll
      for (int off = 4; off < 16; off <<= 1)
        psum[r] += __shfl_xor(psum[r], off, 64);
      l[r] = l[r] * alpha[r] + psum[r];
      acc_o[0][r] *= alpha[r];
      acc_o[1][r] *= alpha[r];
    }

    #pragma unroll
    for (int t = 0; t < 4; ++t)
      #pragma unroll
      for (int r = 0; r < 4; ++r) {
        float p = s4[t][r];
        unsigned short hi = f2b(p);
        unsigned short lo = f2b(p - b2f(hi));
        Pw[wave][0][quad * 4 + r][16 * t + l16] = hi;
        Pw[wave][1][quad * 4 + r][16 * t + l16] = lo;
      }

    #pragma unroll
    for (int kh = 0; kh < 2; ++kh) {
      bf16x8 phi = *(const bf16x8*)&Pw[wave][0][l16][kh * 32 + quad * 8];
      bf16x8 plo = *(const bf16x8*)&Pw[wave][1][l16][kh * 32 + quad * 8];
      #pragma unroll
      for (int nt = 0; nt < 2; ++nt) {
        bf16x8 vf = *(const bf16x8*)&Vt[cur][nt * 16 + l16][kh * 32 + quad * 8];
        acc_o[nt] = __builtin_amdgcn_mfma_f32_16x16x32_bf16(phi, vf, acc_o[nt], 0, 0, 0);
        acc_o[nt] = __builtin_amdgcn_mfma_f32_16x16x32_bf16(plo, vf, acc_o[nt], 0, 0, 0);
      }
    }
  }

  #pragma unroll
  for (int r = 0; r < 4; ++r) {
    float inv = 1.f / l[r];
    size_t rowg = (size_t)b * Ln + i0 + wave * 16 + quad * 4 + r;
    #pragma unroll
    for (int nt = 0; nt < 2; ++nt)
      o[rowg * 512 + hh * 32 + nt * 16 + l16] = f2b(acc_o[nt][r] * inv);
  }
}

// ---------------------------------------------------------------------------
// fp32 tiled GEMM: C = act(A@B + bias), optional bf16 mirror (embed2 / head)
// ---------------------------------------------------------------------------
template<bool RELU, bool BIAS, bool MIRROR>
__global__ __launch_bounds__(256) void gemm64f(
    const float* __restrict__ A, const float* __restrict__ B,
    const float* __restrict__ bias, float* __restrict__ C,
    unsigned short* __restrict__ mir, int N, int K)
{
  __shared__ __align__(16) float As[16][64];
  __shared__ __align__(16) float Bss[16][68];
  const int tid = threadIdx.x;
  const int tx = tid & 15, ty = tid >> 4;
  const int m0 = blockIdx.y * 64, n0 = blockIdx.x * 64;
  const int arow = tid >> 2, acol = (tid & 3) * 4;
  const int brow = tid >> 6, bcol = tid & 63;
  float acc[4][4] = {};
  for (int kb = 0; kb < K; kb += 16) {
    __syncthreads();
    float4 av = *(const float4*)(A + (size_t)(m0 + arow) * K + kb + acol);
    As[acol + 0][arow] = av.x; As[acol + 1][arow] = av.y;
    As[acol + 2][arow] = av.z; As[acol + 3][arow] = av.w;
    #pragma unroll
    for (int kk = 0; kk < 4; ++kk)
      Bss[brow + kk * 4][bcol] = B[(size_t)(kb + brow + kk * 4) * N + n0 + bcol];
    __syncthreads();
    #pragma unroll
    for (int k = 0; k < 16; ++k) {
      float4 a = *(const float4*)&As[k][4 * ty];
      float4 b = *(const float4*)&Bss[k][4 * tx];
      float av4[4] = {a.x, a.y, a.z, a.w};
      float bv4[4] = {b.x, b.y, b.z, b.w};
      #pragma unroll
      for (int ii = 0; ii < 4; ++ii)
        #pragma unroll
        for (int jj = 0; jj < 4; ++jj)
          acc[ii][jj] += av4[ii] * bv4[jj];
    }
  }
  #pragma unroll
  for (int ii = 0; ii < 4; ++ii) {
    size_t row = (size_t)m0 + 4 * ty + ii;
    int col = n0 + 4 * tx;
    float4 vv;
    vv.x = acc[ii][0]; vv.y = acc[ii][1]; vv.z = acc[ii][2]; vv.w = acc[ii][3];
    if (BIAS) {
      float4 bb = *(const float4*)(bias + col);
      vv.x += bb.x; vv.y += bb.y; vv.z += bb.z; vv.w += bb.w;
    }
    if (RELU) {
      vv.x = fmaxf(vv.x, 0.f); vv.y = fmaxf(vv.y, 0.f);
      vv.z = fmaxf(vv.z, 0.f); vv.w = fmaxf(vv.w, 0.f);
    }
    *(float4*)(C + row * N + col) = vv;
    if (MIRROR) {
      ushort4 mv;
      mv.x = f2b(vv.x); mv.y = f2b(vv.y); mv.z = f2b(vv.z); mv.w = f2b(vv.w);
      *(ushort4*)(mir + row * N + col) = mv;
    }
  }
}

__global__ __launch_bounds__(256) void final_r_kernel(
    const float* __restrict__ t1, const float* __restrict__ w2,
    const float* __restrict__ b2, float* __restrict__ r)
{
  int row = blockIdx.x, t = threadIdx.x;
  float xv = t1[(size_t)row * E + t];
  float p0 = xv * w2[t * 3 + 0];
  float p1 = xv * w2[t * 3 + 1];
  float p2 = xv * w2[t * 3 + 2];
  #pragma unroll
  for (int off = 32; off > 0; off >>= 1) {
    p0 += __shfl_down(p0, off, 64);
    p1 += __shfl_down(p1, off, 64);
    p2 += __shfl_down(p2, off, 64);
  }
  __shared__ float red[4][3];
  if ((t & 63) == 0) { int w = t >> 6; red[w][0] = p0; red[w][1] = p1; red[w][2] = p2; }
  __syncthreads();
  if (t < 3)
    r[(size_t)row * 3 + t] = red[0][t] + red[1][t] + red[2][t] + red[3][t] + b2[t];
}

__global__ __launch_bounds__(512) void dist_kernel(
    const float* __restrict__ r, float* __restrict__ out)
{
  int bi = blockIdx.x;
  int j = threadIdx.x;
  int b = bi >> 9;
  float x0 = r[(size_t)bi * 3 + 0];
  float y0 = r[(size_t)bi * 3 + 1];
  float z0 = r[(size_t)bi * 3 + 2];
  const float* rj = r + ((size_t)b * Ln + j) * 3;
  float dx = rj[0] - x0, dy = rj[1] - y0, dz = rj[2] - z0;
  out[(size_t)bi * Ln + j] = sqrtf(dx * dx + dy * dy + dz * dz + 1e-12f);
}

// ---------------------------------------------------------------------------
extern "C" void kernel_launch(void* const* d_in, const int* in_sizes, int n_in,
                              void* d_out, int out_size, void* d_ws, size_t ws_size,
                              hipStream_t stream)
{
  const float* z     = (const float*)d_in[0];
  const float* x     = (const float*)d_in[1];
  const float* pos   = (const float*)d_in[2];
  const float* aa    = (const float*)d_in[3];
  const float* ex_w1 = (const float*)d_in[4];
  const float* ex_b1 = (const float*)d_in[5];
  const float* ex_w2 = (const float*)d_in[6];
  const float* ex_b2 = (const float*)d_in[7];
  const float* Wq    = (const float*)d_in[8];
  const float* Wk    = (const float*)d_in[9];
  const float* Wv    = (const float*)d_in[10];
  const float* Wo    = (const float*)d_in[11];
  const float* bo    = (const float*)d_in[12];
  const float* W2d   = (const float*)d_in[13];
  const float* b2d   = (const float*)d_in[14];
  const float* W1    = (const float*)d_in[15];
  const float* b1    = (const float*)d_in[16];
  const float* W2    = (const float*)d_in[17];
  const float* b2    = (const float*)d_in[18];
  const float* g1    = (const float*)d_in[19];
  const float* be1   = (const float*)d_in[20];
  const float* g2    = (const float*)d_in[21];
  const float* be2   = (const float*)d_in[22];
  const float* m3w1  = (const float*)d_in[23];
  const float* m3b1  = (const float*)d_in[24];
  const float* m3w2  = (const float*)d_in[25];
  const float* m3b2  = (const float*)d_in[26];

  float* ws     = (float*)d_ws;
  float* h      = ws;                          // 4096*256
  float* t0     = h + (size_t)ROWS * E;        // 4096*256 (embed hidden / tmp)
  float* r      = t0 + (size_t)ROWS * E;       // 4096*3
  float* bias49 = r + (size_t)ROWS * 3;        // 8*16*49
  unsigned short* us = (unsigned short*)(bias49 + NL * NH * 49);
  unsigned short* hb   = us;                              // 4096*256
  unsigned short* umb  = hb  + (size_t)ROWS * E;          // 4096*288
  unsigned short* qkvb = umb + (size_t)ROWS * (E + E1D);  // 4096*1536
  unsigned short* ob   = qkvb + (size_t)ROWS * 3 * DM;    // 4096*512
  unsigned short* t1b  = ob  + (size_t)ROWS * DM;         // 4096*1024
  unsigned short* qkvT = t1b + (size_t)ROWS * FF;         // 8*1536*256
  unsigned short* WoT  = qkvT + (size_t)NL * 3 * DM * E;  // 8*256*512
  unsigned short* W1T  = WoT  + (size_t)NL * E * DM;      // 8*1024*288
  unsigned short* W2T  = W1T  + (size_t)NL * FF * (E+E1D);// 8*256*1024
  float* t1f = (float*)t1b;   // head scratch aliases t1b

  // ---- weight transpose+convert (4 launches) ----
  transpose_qkv<<<dim3(DM/32, E/32, 3*NL), 256, 0, stream>>>(Wq, Wk, Wv, qkvT);
  transpose_bf16<<<dim3(E/32, DM/32, NL), 256, 0, stream>>>(
      Wo, WoT, DM, E, (size_t)DM * E, (size_t)DM * E);
  transpose_bf16<<<dim3(FF/32, (E+E1D)/32, NL), 256, 0, stream>>>(
      W1, W1T, E + E1D, FF, (size_t)(E+E1D) * FF, (size_t)(E+E1D) * FF);
  transpose_bf16<<<dim3(E/32, FF/32, NL), 256, 0, stream>>>(
      W2, W2T, FF, E, (size_t)FF * E, (size_t)FF * E);

  embed1_kernel<<<ROWS, 256, 0, stream>>>(z, x, aa, ex_w1, ex_b1, t0, umb);
  gemm64f<false,true,true><<<dim3(E/64, ROWS/64), 256, 0, stream>>>(
      t0, ex_w2, ex_b2, h, hb, E, E);
  bias_kernel<<<NL, 256, 0, stream>>>(pos, W2d, b2d, bias49);

  for (int i = 0; i < NL; ++i) {
    // fused QKV: N=1536, 64x128 tiles, BK=128 -> 768 blocks (3/CU), 2 K-steps
    gemm_mfma<64,128,128,false,false,true,true><<<dim3(12, 64), 256, 0, stream>>>(
        hb, qkvT + (size_t)i * 3 * DM * E, nullptr, nullptr, qkvb, 3 * DM, E);
    // attention: 1D grid 1024 with XCD-locality remap
    attn_kernel<<<dim3(1024), 256, 0, stream>>>(
        qkvb, bias49 + (size_t)i * NH * 49, ob);
    // fused Wo + bias + resid + LN1 -> h, umb  (256 blocks, pipelined)
    gemm_ln<<<ROWS/16, 256, 0, stream>>>(
        ob, WoT + (size_t)i * DM * E, bo + (size_t)i * E, h,
        g1 + (size_t)i * E, be1 + (size_t)i * E, umb, E + E1D, DM);
    // FF1 + bias + relu -> bf16 t1b  (64x64 tiles, BK=32 -> 1024 blocks, 4/CU)
    gemm_mfma<64,64,32,true,true,true,false><<<dim3(FF/64, ROWS/64), 256, 0, stream>>>(
        umb, W1T + (size_t)i * FF * (E+E1D), b1 + (size_t)i * FF, nullptr, t1b, FF, E + E1D);
    // fused FF2 + bias + resid + LN2 -> h, hb  (256 blocks, pipelined)
    gemm_ln<<<ROWS/16, 256, 0, stream>>>(
        t1b, W2T + (size_t)i * E * FF, b2 + (size_t)i * E, h,
        g2 + (size_t)i * E, be2 + (size_t)i * E, hb, E, FF);
  }

  // fp32 head
  gemm64f<true,true,false><<<dim3(E/64, ROWS/64), 256, 0, stream>>>(
      h, m3w1, m3b1, t1f, nullptr, E, E);
  final_r_kernel<<<ROWS, 256, 0, stream>>>(t1f, m3w2, m3b2, r);
  dist_kernel<<<ROWS, 512, 0, stream>>>(r, (float*)d_out);
}